// Round 1
// baseline (133.197 us; speedup 1.0000x reference)
//
#include <hip/hip_runtime.h>
#include <hip/hip_bf16.h>
#include <stdint.h>

// Problem constants
#define BB 16
#define SS 512
#define TT 16
#define DD 128
#define NROWS (BB*SS*TT)        // 131072 rows of D=128
#define LN_EPS 1e-5f

typedef __attribute__((ext_vector_type(8))) short short8;
typedef __attribute__((ext_vector_type(4))) float f32x4;

static __device__ __forceinline__ unsigned short f2bf(float f) {
    unsigned int u = __float_as_uint(f);
    u += 0x7fffu + ((u >> 16) & 1u);   // round-to-nearest-even
    return (unsigned short)(u >> 16);
}

// -----------------------------------------------------------------------------
// K1: fused LayerNorm + GEMM (xn @ W + b) + gate/value activation.
// Block: 256 threads (4 waves). Each block handles 64 rows (4 M-tiles of 16).
// Wave w owns output n-tiles {2w, 2w+1} (gate cols) and {8+2w, 8+2w+1} (hidden
// cols); W fragments live in registers for the whole block (64 VGPRs/lane).
// xn staged in LDS (bf16) with XOR-swizzle: byte ^= ((row&7)<<4) on 16B chunks.
// -----------------------------------------------------------------------------
__global__ __launch_bounds__(256) void k1_ln_gemm_act(
    const float* __restrict__ x, const float* __restrict__ gamma,
    const float* __restrict__ beta, const float* __restrict__ W,
    const float* __restrict__ bias, float* __restrict__ cP, float* __restrict__ vP)
{
    __shared__ __align__(16) unsigned char lds[16 * 256];   // 16 rows x 128 bf16

    const int w    = threadIdx.x >> 6;       // wave 0..3
    const int lane = threadIdx.x & 63;
    const int l15  = lane & 15;
    const int lhi  = lane >> 4;              // 0..3

    // ---- preload W fragments + bias (constant for the whole block) ----
    short8 wf[4][4];
    float  bs[4];
    #pragma unroll
    for (int ni = 0; ni < 4; ++ni) {
        const int nt  = (ni < 2) ? (2*w + ni) : (8 + 2*w + (ni - 2));
        const int col = nt*16 + l15;
        bs[ni] = bias[col];
        #pragma unroll
        for (int kt = 0; kt < 4; ++kt) {
            #pragma unroll
            for (int j = 0; j < 8; ++j) {
                const int k = kt*32 + lhi*8 + j;
                wf[ni][kt][j] = (short)f2bf(W[(size_t)k*256 + col]);
            }
        }
    }

    // ---- per-thread LN lane assignment (constant across M-tiles) ----
    const int lr = threadIdx.x >> 4;   // row within 16-row tile (0..15)
    const int ck = threadIdx.x & 15;   // 16B chunk (8 f32 elems) within the row
    const float4 g0 = *(const float4*)(gamma + ck*8);
    const float4 g1 = *(const float4*)(gamma + ck*8 + 4);
    const float4 b0 = *(const float4*)(beta  + ck*8);
    const float4 b1 = *(const float4*)(beta  + ck*8 + 4);

    const int rowbase = blockIdx.x * 64;

    for (int mt = 0; mt < 4; ++mt) {
        const int r0 = rowbase + mt*16;

        // ---- LayerNorm of row (r0+lr), chunk ck ----
        const float* xp = x + (size_t)(r0 + lr)*DD + ck*8;
        const float4 v0 = *(const float4*)xp;
        const float4 v1 = *(const float4*)(xp + 4);
        float s1 = v0.x+v0.y+v0.z+v0.w + v1.x+v1.y+v1.z+v1.w;
        float s2 = v0.x*v0.x+v0.y*v0.y+v0.z*v0.z+v0.w*v0.w
                 + v1.x*v1.x+v1.y*v1.y+v1.z*v1.z+v1.w*v1.w;
        #pragma unroll
        for (int m = 1; m < 16; m <<= 1) {
            s1 += __shfl_xor(s1, m);
            s2 += __shfl_xor(s2, m);
        }
        const float mu = s1 * (1.0f/128.0f);
        const float rs = rsqrtf(s2 * (1.0f/128.0f) - mu*mu + LN_EPS);

        const float xv[8] = {v0.x,v0.y,v0.z,v0.w,v1.x,v1.y,v1.z,v1.w};
        const float gv[8] = {g0.x,g0.y,g0.z,g0.w,g1.x,g1.y,g1.z,g1.w};
        const float bv[8] = {b0.x,b0.y,b0.z,b0.w,b1.x,b1.y,b1.z,b1.w};
        short8 sv;
        #pragma unroll
        for (int j = 0; j < 8; ++j) {
            const float xn = (xv[j] - mu) * rs * gv[j] + bv[j];
            sv[j] = (short)f2bf(xn);
        }
        // swizzled LDS write: row lr, chunk ck
        *(short8*)(lds + lr*256 + ((ck ^ (lr & 7)) << 4)) = sv;
        __syncthreads();

        // ---- A fragments: row = l15, k-chunk = kt*4 + lhi (swizzled read) ----
        short8 af[4];
        #pragma unroll
        for (int kt = 0; kt < 4; ++kt) {
            const int chunk = (kt << 2) | lhi;
            af[kt] = *(const short8*)(lds + l15*256 + ((chunk ^ (l15 & 7)) << 4));
        }
        __syncthreads();   // LDS free for next M-tile

        // ---- MFMA: acc over K=128 (4 k-tiles) for 2 gate + 2 hidden n-tiles ----
        f32x4 accg[2] = {(f32x4)(0.0f), (f32x4)(0.0f)};
        f32x4 acch[2] = {(f32x4)(0.0f), (f32x4)(0.0f)};
        #pragma unroll
        for (int kt = 0; kt < 4; ++kt) {
            #pragma unroll
            for (int i = 0; i < 2; ++i) {
                accg[i] = __builtin_amdgcn_mfma_f32_16x16x32_bf16(af[kt], wf[i][kt],   accg[i], 0, 0, 0);
                acch[i] = __builtin_amdgcn_mfma_f32_16x16x32_bf16(af[kt], wf[2+i][kt], acch[i], 0, 0, 0);
            }
        }

        // ---- activation epilogue: c = sigmoid(-g), v = sigmoid(g)*gact(h) ----
        #pragma unroll
        for (int i = 0; i < 2; ++i) {
            const int dcol = (2*w + i)*16 + l15;    // 0..127
            #pragma unroll
            for (int j = 0; j < 4; ++j) {
                const int row = r0 + lhi*4 + j;
                const float g = accg[i][j] + bs[i];
                const float h = acch[i][j] + bs[2+i];
                const float c = 1.0f / (1.0f + __expf(g));
                const float ga = (h >= 0.0f) ? (h + 0.5f)
                                             : (1.0f / (1.0f + __expf(-h)));
                const float v = (1.0f - c) * ga;
                const size_t off = (size_t)row*DD + dcol;
                cP[off] = c;
                vP[off] = v;
            }
        }
    }
}

// -----------------------------------------------------------------------------
// K2: sequential scan along S. One thread per (b,t,d) chain (32768 chains).
// h_s = c_s*h_{s-1} + v_s ; out[b,s,t,d] = h_s ; nexth = h_{S-1}.
// Coalesced along d (consecutive lanes), stride T*D between steps.
// -----------------------------------------------------------------------------
__global__ __launch_bounds__(64) void k2_scan(
    const float* __restrict__ cP, const float* __restrict__ vP,
    const float* __restrict__ prevh, float* __restrict__ out,
    float* __restrict__ nexth)
{
    const int tid = blockIdx.x * 64 + threadIdx.x;   // 0..32767
    const int d   = tid & (DD - 1);
    const int bt  = tid >> 7;                        // b*T + t
    const int b   = bt >> 4;
    const int t   = bt & 15;

    float h = prevh[(size_t)bt*DD + d];
    const size_t base   = ((size_t)b*SS*TT + t) * DD + d;
    const size_t stride = (size_t)TT * DD;           // 2048

    #pragma unroll 8
    for (int s = 0; s < SS; ++s) {
        const size_t off = base + (size_t)s * stride;
        const float c = cP[off];
        const float v = vP[off];
        h = fmaf(c, h, v);
        out[off] = h;
    }
    nexth[(size_t)bt*DD + d] = h;
}

extern "C" void kernel_launch(void* const* d_in, const int* in_sizes, int n_in,
                              void* d_out, int out_size, void* d_ws, size_t ws_size,
                              hipStream_t stream) {
    const float* x     = (const float*)d_in[0];
    const float* prevh = (const float*)d_in[1];
    const float* gamma = (const float*)d_in[2];
    const float* beta  = (const float*)d_in[3];
    const float* W     = (const float*)d_in[4];
    const float* bias  = (const float*)d_in[5];

    float* out   = (float*)d_out;
    float* nexth = out + (size_t)NROWS * DD;         // 16777216

    const size_t plane = (size_t)NROWS * DD;         // elems per plane
    float* cP;
    float* vP;
    if (ws_size >= plane * 8) {                      // both planes fit in ws
        cP = (float*)d_ws;
        vP = cP + plane;
    } else {                                         // fallback: c reuses out
        cP = out;
        vP = (float*)d_ws;
    }

    k1_ln_gemm_act<<<NROWS/64, 256, 0, stream>>>(x, gamma, beta, W, bias, cP, vP);
    k2_scan<<<(BB*TT*DD)/64, 64, 0, stream>>>(cP, vP, prevh, out, nexth);
}

// Round 3
// 65.898 us; speedup vs baseline: 2.0213x; 2.0213x over previous
//
#include <hip/hip_runtime.h>
#include <hip/hip_bf16.h>
#include <stdint.h>

// Problem constants
#define BB 16
#define SS 512
#define TT 16
#define DD 128
#define CH 64                 // s-chunk per pipeline stage
#define NCH (SS/CH)           // 8
#define LN_EPS 1e-5f

typedef __attribute__((ext_vector_type(8))) short short8;
typedef __attribute__((ext_vector_type(4))) float f32x4;

static __device__ __forceinline__ unsigned short f2bf(float f) {
    unsigned int u = __float_as_uint(f);
    u += 0x7fffu + ((u >> 16) & 1u);   // round-to-nearest-even
    return (unsigned short)(u >> 16);
}

// -----------------------------------------------------------------------------
// k0: fold LN affine into the GEMM and pack fragments.
//   W'[k,col] = gamma[k] * W[k,col]   (bf16, MFMA B-fragment order)
//   b'[col]   = bias[col] + sum_k beta[k] * W[k,col]   (f32)
// Fragment layout: flat id = (((w*4+ni)*4+kt)*64 + lane)*8 + j
//   nt = ni<2 ? 2w+ni : 8+2w+(ni-2); col = nt*16+(lane&15); k = kt*32+(lane>>4)*8+j
// -----------------------------------------------------------------------------
__global__ __launch_bounds__(256) void k0_pack(
    const float* __restrict__ W, const float* __restrict__ gamma,
    const float* __restrict__ beta, const float* __restrict__ bias,
    unsigned short* __restrict__ wf, float* __restrict__ bp)
{
    if (blockIdx.x < 128) {
        const int id   = blockIdx.x * 256 + threadIdx.x;   // 0..32767
        const int j    = id & 7;
        const int lane = (id >> 3) & 63;
        const int kt   = (id >> 9) & 3;
        const int ni   = (id >> 11) & 3;
        const int w    = (id >> 13) & 3;
        const int nt   = (ni < 2) ? (2*w + ni) : (8 + 2*w + (ni - 2));
        const int col  = nt*16 + (lane & 15);
        const int k    = kt*32 + (lane >> 4)*8 + j;
        wf[id] = f2bf(gamma[k] * W[(size_t)k*256 + col]);
    } else {
        const int col = threadIdx.x;                        // 0..255
        float s = bias[col];
        #pragma unroll 8
        for (int k = 0; k < 128; ++k)
            s = fmaf(beta[k], W[(size_t)k*256 + col], s);
        bp[col] = s;
    }
}

// -----------------------------------------------------------------------------
// Fused LN + GEMM + activation + scan. One block per (b,t) chain group.
// 4 waves. Pipeline per 64-step chunk:
//   B(ch): all 4 waves MFMA xn[ch] -> c,v into LDS
//   bar
//   C(ch): waves 0-1 scan 64 steps from LDS, store out   (h in registers)
//   A(ch+1): waves 2-3 load x, LayerNorm, write xn double-buffer
//   bar
// c/v never touch HBM.
// -----------------------------------------------------------------------------
__global__ __launch_bounds__(256, 1) void fused_mingru(
    const float* __restrict__ x, const float* __restrict__ prevh,
    const unsigned short* __restrict__ wfrag, const float* __restrict__ bp,
    float* __restrict__ out, float* __restrict__ nexth)
{
    __shared__ __align__(16) unsigned char xnb[2][CH*256];  // 2 x 16 KB bf16 xn
    __shared__ float cbuf[CH][DD];                          // 32 KB
    __shared__ float vbuf[CH][DD];                          // 32 KB

    const int tid  = threadIdx.x;
    const int w    = tid >> 6;
    const int lane = tid & 63;
    const int l15  = lane & 15;
    const int lhi  = lane >> 4;
    const int b    = blockIdx.x >> 4;
    const int t    = blockIdx.x & 15;

    // ---- W fragments (bf16, pre-packed) + folded bias ----
    short8 wfr[4][4];
    #pragma unroll
    for (int ni = 0; ni < 4; ++ni)
        #pragma unroll
        for (int kt = 0; kt < 4; ++kt)
            wfr[ni][kt] = *(const short8*)(wfrag + (size_t)(((w*4+ni)*4+kt)*64 + lane)*8);
    float bs[4];
    #pragma unroll
    for (int ni = 0; ni < 4; ++ni) {
        const int nt = (ni < 2) ? (2*w + ni) : (8 + 2*w + (ni - 2));
        bs[ni] = bp[nt*16 + l15];
    }

    const size_t rowstride = (size_t)TT * DD;               // 2048
    const size_t base_bt   = ((size_t)b * SS * TT + t) * DD;

    float h = 0.0f;
    if (tid < 128) h = prevh[((size_t)b*16 + t)*128 + tid];

    // ---- Phase A: waves 2-3 (128 threads) load + LN one chunk ----
    auto phaseA = [&](int ch, int pbuf) {
        const int tid2 = tid - 128;
        const int ls   = tid2 >> 1;       // local s (0..63)
        const int half = tid2 & 1;        // which 64-float half of the row
        const float* xr = x + base_bt + (size_t)(ch*CH + ls)*rowstride + half*64;
        float4 v[16];
        #pragma unroll
        for (int i = 0; i < 16; ++i) v[i] = *(const float4*)(xr + i*4);
        float s1 = 0.f, s2 = 0.f;
        #pragma unroll
        for (int i = 0; i < 16; ++i) {
            s1 += v[i].x + v[i].y + v[i].z + v[i].w;
            s2 += v[i].x*v[i].x + v[i].y*v[i].y + v[i].z*v[i].z + v[i].w*v[i].w;
        }
        s1 += __shfl_xor(s1, 1);
        s2 += __shfl_xor(s2, 1);
        const float mu = s1 * (1.0f/128.0f);
        const float rs = rsqrtf(s2 * (1.0f/128.0f) - mu*mu + LN_EPS);
        unsigned char* row = xnb[pbuf] + ls*256;
        #pragma unroll
        for (int q = 0; q < 8; ++q) {
            const float4 va = v[2*q], vb = v[2*q+1];
            const float fe[8] = {va.x,va.y,va.z,va.w, vb.x,vb.y,vb.z,vb.w};
            short8 sv;
            #pragma unroll
            for (int e = 0; e < 8; ++e)
                sv[e] = (short)f2bf((fe[e] - mu) * rs);
            const int c = half*8 + q;     // 16B chunk index 0..15
            *(short8*)(row + ((c ^ (ls & 7)) << 4)) = sv;
        }
    };

    // ---- Phase B: all 4 waves, MFMA + activation -> cbuf/vbuf ----
    auto phaseB = [&](int pbuf) {
        #pragma unroll
        for (int mt = 0; mt < 4; ++mt) {
            const unsigned char* rowp = xnb[pbuf] + (mt*16 + l15)*256;
            short8 af[4];
            #pragma unroll
            for (int kt = 0; kt < 4; ++kt) {
                const int c = (kt << 2) | lhi;
                af[kt] = *(const short8*)(rowp + ((c ^ (l15 & 7)) << 4));
            }
            f32x4 ag[2] = {(f32x4)(0.f), (f32x4)(0.f)};
            f32x4 ah[2] = {(f32x4)(0.f), (f32x4)(0.f)};
            #pragma unroll
            for (int kt = 0; kt < 4; ++kt) {
                #pragma unroll
                for (int i = 0; i < 2; ++i) {
                    ag[i] = __builtin_amdgcn_mfma_f32_16x16x32_bf16(af[kt], wfr[i][kt],   ag[i], 0, 0, 0);
                    ah[i] = __builtin_amdgcn_mfma_f32_16x16x32_bf16(af[kt], wfr[2+i][kt], ah[i], 0, 0, 0);
                }
            }
            #pragma unroll
            for (int i = 0; i < 2; ++i) {
                const int d = (2*w + i)*16 + l15;   // 0..127 (gate col == hidden col-128)
                #pragma unroll
                for (int j = 0; j < 4; ++j) {
                    const int ls = mt*16 + lhi*4 + j;
                    const float g = ag[i][j] + bs[i];
                    const float hh = ah[i][j] + bs[2+i];
                    const float c = 1.0f / (1.0f + __expf(g));
                    const float ga = (hh >= 0.0f) ? (hh + 0.5f)
                                                  : (1.0f / (1.0f + __expf(-hh)));
                    cbuf[ls][d] = c;
                    vbuf[ls][d] = (1.0f - c) * ga;
                }
            }
        }
    };

    // ---- Phase C: waves 0-1 (128 threads), sequential scan of the chunk ----
    auto phaseC = [&](int ch) {
        float* op = out + base_bt + (size_t)(ch*CH)*rowstride + tid;
        #pragma unroll 8
        for (int ls = 0; ls < CH; ++ls) {
            h = fmaf(cbuf[ls][tid], h, vbuf[ls][tid]);
            op[(size_t)ls * rowstride] = h;
        }
    };

    // ---- pipeline ----
    if (w >= 2) phaseA(0, 0);
    __syncthreads();
    int pbuf = 0;
    for (int ch = 0; ch < NCH; ++ch) {
        phaseB(pbuf);
        __syncthreads();
        if (w < 2) phaseC(ch);
        else if (ch + 1 < NCH) phaseA(ch + 1, pbuf ^ 1);
        __syncthreads();
        pbuf ^= 1;
    }
    if (tid < 128) nexth[((size_t)b*16 + t)*128 + tid] = h;
}

extern "C" void kernel_launch(void* const* d_in, const int* in_sizes, int n_in,
                              void* d_out, int out_size, void* d_ws, size_t ws_size,
                              hipStream_t stream) {
    const float* x     = (const float*)d_in[0];
    const float* prevh = (const float*)d_in[1];
    const float* gamma = (const float*)d_in[2];
    const float* beta  = (const float*)d_in[3];
    const float* W     = (const float*)d_in[4];
    const float* bias  = (const float*)d_in[5];

    float* out   = (float*)d_out;
    float* nexth = out + (size_t)BB*SS*TT*DD;              // 16777216

    unsigned short* wf = (unsigned short*)d_ws;            // 64 KB fragments
    float*          bpf = (float*)((char*)d_ws + 65536);   // 1 KB folded bias

    k0_pack<<<129, 256, 0, stream>>>(W, gamma, beta, bias, wf, bpf);
    fused_mingru<<<BB*TT, 256, 0, stream>>>(x, prevh, wf, bpf, out, nexth);
}

// Round 5
// 65.739 us; speedup vs baseline: 2.0261x; 1.0024x over previous
//
#include <hip/hip_runtime.h>
#include <hip/hip_bf16.h>
#include <stdint.h>

// Problem constants
#define BB 16
#define SS 512
#define TT 16
#define DD 128
#define CH 64                 // s-chunk per pipeline stage
#define NCH (SS/CH)           // 8
#define LN_EPS 1e-5f

typedef __attribute__((ext_vector_type(8))) short short8;
typedef __attribute__((ext_vector_type(4))) float f32x4;

static __device__ __forceinline__ unsigned short f2bf(float f) {
    unsigned int u = __float_as_uint(f);
    u += 0x7fffu + ((u >> 16) & 1u);   // round-to-nearest-even
    return (unsigned short)(u >> 16);
}

// Barrier that does NOT drain vmcnt: LDS ordering only. Global prefetch loads
// (register destinations, consumed only by the issuing thread) stay in flight
// across it — the T14 async-STAGE recipe (guide §6 G15, m214 r277).
#define BAR() do {                                            \
    asm volatile("s_waitcnt lgkmcnt(0)" ::: "memory");        \
    __builtin_amdgcn_s_barrier();                             \
    asm volatile("" ::: "memory");                            \
} while (0)

// -----------------------------------------------------------------------------
// k0: fold LN affine into the GEMM and pack fragments.
//   W'[k,col] = gamma[k] * W[k,col]   (bf16, MFMA B-fragment order)
//   b'[col]   = bias[col] + sum_k beta[k] * W[k,col]   (f32)
// -----------------------------------------------------------------------------
__global__ __launch_bounds__(256) void k0_pack(
    const float* __restrict__ W, const float* __restrict__ gamma,
    const float* __restrict__ beta, const float* __restrict__ bias,
    unsigned short* __restrict__ wf, float* __restrict__ bp)
{
    if (blockIdx.x < 128) {
        const int id   = blockIdx.x * 256 + threadIdx.x;   // 0..32767
        const int j    = id & 7;
        const int lane = (id >> 3) & 63;
        const int kt   = (id >> 9) & 3;
        const int ni   = (id >> 11) & 3;
        const int w    = (id >> 13) & 3;
        const int nt   = (ni < 2) ? (2*w + ni) : (8 + 2*w + (ni - 2));
        const int col  = nt*16 + (lane & 15);
        const int k    = kt*32 + (lane >> 4)*8 + j;
        wf[id] = f2bf(gamma[k] * W[(size_t)k*256 + col]);
    } else {
        const int col = threadIdx.x;                        // 0..255
        float s = bias[col];
        #pragma unroll 8
        for (int k = 0; k < 128; ++k)
            s = fmaf(beta[k], W[(size_t)k*256 + col], s);
        bp[col] = s;
    }
}

// -----------------------------------------------------------------------------
// Fused LN + GEMM + activation + scan, one block per (b,t). 4 waves.
// Steady state per 64-step chunk ch:
//   B(ch): all waves MFMA xn[ch] + activation -> cvb (float2 c,v in LDS)
//   BAR
//   w01: scan 64 steps from cvb, store out        (h in registers)
//   w23: finish LN(ch+1) from prefetch regs -> xn[ch+1]; issue loads(ch+2)
//   BAR
// x-loads are issued one full chunk ahead and stay in flight across both
// barriers and phase B (BAR does not drain vmcnt).
// -----------------------------------------------------------------------------
__global__ __launch_bounds__(256, 1) void fused_mingru(
    const float* __restrict__ x, const float* __restrict__ prevh,
    const unsigned short* __restrict__ wfrag, const float* __restrict__ bp,
    float* __restrict__ out, float* __restrict__ nexth)
{
    __shared__ __align__(16) unsigned char xnb[2][CH*256];  // 2 x 16 KB bf16 xn
    __shared__ __align__(16) float2 cvb[CH][DD];            // 64 KB interleaved c,v

    const int tid  = threadIdx.x;
    const int w    = tid >> 6;
    const int lane = tid & 63;
    const int l15  = lane & 15;
    const int lhi  = lane >> 4;

    // ---- W fragments (bf16, pre-packed) + folded bias ----
    short8 wfr[4][4];
    #pragma unroll
    for (int ni = 0; ni < 4; ++ni)
        #pragma unroll
        for (int kt = 0; kt < 4; ++kt)
            wfr[ni][kt] = *(const short8*)(wfrag + (size_t)(((w*4+ni)*4+kt)*64 + lane)*8);
    float bs[4];
    #pragma unroll
    for (int ni = 0; ni < 4; ++ni) {
        const int nt = (ni < 2) ? (2*w + ni) : (8 + 2*w + (ni - 2));
        bs[ni] = bp[nt*16 + l15];
    }

    const size_t rowstride = (size_t)TT * DD;               // 2048
    const size_t base_bt   = ((size_t)(blockIdx.x >> 4) * SS * TT + (blockIdx.x & 15)) * DD;

    float h = 0.0f;
    if (tid < 128) h = prevh[(size_t)blockIdx.x * 128 + tid];

    // ---- prefetch state (meaningful for waves 2-3 only) ----
    const int tid2 = tid & 127;          // w23: tid-128
    const int ls_a = tid2 >> 1;          // row within chunk (0..63)
    const int half = tid2 & 1;           // which 64-float half of the row
    const float* xbase = x + base_bt + (size_t)ls_a * rowstride + half*64;
    float4 vx[16];

    auto issueA = [&](int ch) {          // issue 16 float4 loads, no wait
        const float* xr = xbase + (size_t)ch * CH * rowstride;
        #pragma unroll
        for (int i = 0; i < 16; ++i) vx[i] = ((const float4*)xr)[i];
    };

    auto finA = [&](int pbuf) {          // reduce + bf16 + swizzled LDS write
        float s1 = 0.f, s2 = 0.f;
        #pragma unroll
        for (int i = 0; i < 16; ++i) {
            s1 += vx[i].x + vx[i].y + vx[i].z + vx[i].w;
            s2 += vx[i].x*vx[i].x + vx[i].y*vx[i].y + vx[i].z*vx[i].z + vx[i].w*vx[i].w;
        }
        s1 += __shfl_xor(s1, 1);
        s2 += __shfl_xor(s2, 1);
        const float mu = s1 * (1.0f/128.0f);
        const float rs = rsqrtf(s2 * (1.0f/128.0f) - mu*mu + LN_EPS);
        unsigned char* row = xnb[pbuf] + ls_a*256;
        #pragma unroll
        for (int q = 0; q < 8; ++q) {
            const float4 va = vx[2*q], vb = vx[2*q+1];
            const float fe[8] = {va.x,va.y,va.z,va.w, vb.x,vb.y,vb.z,vb.w};
            short8 sv;
            #pragma unroll
            for (int e = 0; e < 8; ++e)
                sv[e] = (short)f2bf((fe[e] - mu) * rs);
            const int c = half*8 + q;                        // 16B chunk 0..15
            *(short8*)(row + ((c ^ (ls_a & 7)) << 4)) = sv;
        }
    };

    auto phaseB = [&](int pbuf) {
        #pragma unroll
        for (int mt = 0; mt < 4; ++mt) {
            const unsigned char* rowp = xnb[pbuf] + (mt*16 + l15)*256;
            short8 af[4];
            #pragma unroll
            for (int kt = 0; kt < 4; ++kt) {
                const int c = (kt << 2) | lhi;
                af[kt] = *(const short8*)(rowp + ((c ^ (l15 & 7)) << 4));
            }
            f32x4 ag[2] = {(f32x4)(0.f), (f32x4)(0.f)};
            f32x4 ah[2] = {(f32x4)(0.f), (f32x4)(0.f)};
            #pragma unroll
            for (int kt = 0; kt < 4; ++kt) {
                #pragma unroll
                for (int i = 0; i < 2; ++i) {
                    ag[i] = __builtin_amdgcn_mfma_f32_16x16x32_bf16(af[kt], wfr[i][kt],   ag[i], 0, 0, 0);
                    ah[i] = __builtin_amdgcn_mfma_f32_16x16x32_bf16(af[kt], wfr[2+i][kt], ah[i], 0, 0, 0);
                }
            }
            #pragma unroll
            for (int i = 0; i < 2; ++i) {
                const int d = (2*w + i)*16 + l15;            // 0..127
                #pragma unroll
                for (int j = 0; j < 4; ++j) {
                    const int ls = mt*16 + lhi*4 + j;
                    const float g  = ag[i][j] + bs[i];
                    const float hh = ah[i][j] + bs[2+i];
                    const float c  = 1.0f / (1.0f + __expf(g));
                    const float ga = (hh >= 0.0f) ? (hh + 0.5f)
                                                  : (1.0f / (1.0f + __expf(-hh)));
                    cvb[ls][d] = make_float2(c, (1.0f - c) * ga);
                }
            }
        }
    };

    auto phaseC = [&](int ch) {          // waves 0-1: sequential scan
        float* op = out + base_bt + (size_t)ch * CH * rowstride + tid;
        #pragma unroll 8
        for (int ls = 0; ls < CH; ++ls) {
            const float2 cv = cvb[ls][tid];
            h = fmaf(cv.x, h, cv.y);
            op[(size_t)ls * rowstride] = h;
        }
    };

    // ---- prologue: LN chunk 0 (exposed latency once), prefetch chunk 1 ----
    if (w >= 2) {
        issueA(0);
        finA(0);
        issueA(1);
    }
    BAR();

    int pbuf = 0;
    for (int ch = 0; ch < NCH; ++ch) {
        phaseB(pbuf);
        BAR();
        if (w < 2) {
            phaseC(ch);
        } else {
            if (ch + 1 < NCH) {
                finA(pbuf ^ 1);                 // consume loads issued at ch-1
                if (ch + 2 < NCH) issueA(ch + 2);
            }
        }
        BAR();
        pbuf ^= 1;
    }
    if (tid < 128) nexth[(size_t)blockIdx.x * 128 + tid] = h;
}

extern "C" void kernel_launch(void* const* d_in, const int* in_sizes, int n_in,
                              void* d_out, int out_size, void* d_ws, size_t ws_size,
                              hipStream_t stream) {
    const float* x     = (const float*)d_in[0];
    const float* prevh = (const float*)d_in[1];
    const float* gamma = (const float*)d_in[2];
    const float* beta  = (const float*)d_in[3];
    const float* W     = (const float*)d_in[4];
    const float* bias  = (const float*)d_in[5];

    float* out   = (float*)d_out;
    float* nexth = out + (size_t)BB*SS*TT*DD;              // 16777216

    unsigned short* wf  = (unsigned short*)d_ws;           // 64 KB fragments
    float*          bpf = (float*)((char*)d_ws + 65536);   // 1 KB folded bias

    k0_pack<<<129, 256, 0, stream>>>(W, gamma, beta, bias, wf, bpf);
    fused_mingru<<<BB*TT, 256, 0, stream>>>(x, prevh, wf, bpf, out, nexth);
}

// Round 6
// 60.154 us; speedup vs baseline: 2.2143x; 1.0928x over previous
//
#include <hip/hip_runtime.h>
#include <hip/hip_bf16.h>
#include <stdint.h>

// Problem constants
#define BB 16
#define SS 512
#define TT 16
#define DD 128
#define CH 64                 // s-chunk per pipeline stage
#define NCH (SS/CH)           // 8
#define LN_EPS 1e-5f

typedef __attribute__((ext_vector_type(8))) short short8;
typedef __attribute__((ext_vector_type(4))) float f32x4;

static __device__ __forceinline__ unsigned short f2bf(float f) {
    unsigned int u = __float_as_uint(f);
    u += 0x7fffu + ((u >> 16) & 1u);   // round-to-nearest-even
    return (unsigned short)(u >> 16);
}

// async global->LDS DMA, 16B per lane, LDS dest = uniform base + lane*16
static __device__ __forceinline__ void dma16(const float* g, unsigned char* l) {
    __builtin_amdgcn_global_load_lds(
        (const __attribute__((address_space(1))) unsigned int*)g,
        (__attribute__((address_space(3))) unsigned int*)l, 16, 0, 0);
}

// Barrier that does NOT drain vmcnt: LDS ordering only. DMA loads stay in
// flight across it; the issuing wave drains them with a counted vmcnt wait.
#define BAR() do {                                            \
    asm volatile("s_waitcnt lgkmcnt(0)" ::: "memory");        \
    __builtin_amdgcn_s_barrier();                             \
    asm volatile("" ::: "memory");                            \
} while (0)

// -----------------------------------------------------------------------------
// k0: fold LN affine into the GEMM and pack fragments.
//   W'[k,col] = gamma[k] * W[k,col]   (bf16, MFMA B-fragment order)
//   b'[col]   = bias[col] + sum_k beta[k] * W[k,col]   (f32)
// -----------------------------------------------------------------------------
__global__ __launch_bounds__(256) void k0_pack(
    const float* __restrict__ W, const float* __restrict__ gamma,
    const float* __restrict__ beta, const float* __restrict__ bias,
    unsigned short* __restrict__ wf, float* __restrict__ bp)
{
    if (blockIdx.x < 128) {
        const int id   = blockIdx.x * 256 + threadIdx.x;   // 0..32767
        const int j    = id & 7;
        const int lane = (id >> 3) & 63;
        const int kt   = (id >> 9) & 3;
        const int ni   = (id >> 11) & 3;
        const int w    = (id >> 13) & 3;
        const int nt   = (ni < 2) ? (2*w + ni) : (8 + 2*w + (ni - 2));
        const int col  = nt*16 + (lane & 15);
        const int k    = kt*32 + (lane >> 4)*8 + j;
        wf[id] = f2bf(gamma[k] * W[(size_t)k*256 + col]);
    } else {
        const int col = threadIdx.x;                        // 0..255
        float s = bias[col];
        #pragma unroll 8
        for (int k = 0; k < 128; ++k)
            s = fmaf(beta[k], W[(size_t)k*256 + col], s);
        bp[col] = s;
    }
}

// -----------------------------------------------------------------------------
// Fused LN + GEMM + activation + scan, one block per (b,t). 4 waves.
// x is DMA-staged into LDS (double-buffered, source-swizzled). Steady state:
//   B(ch): all waves MFMA xnb -> cvb
//   BAR
//   w01: scan 64 steps from cvb, store out
//   w23: vmcnt(0) [x(ch+1) DMA done]; LN Xb[(ch+1)&1] -> xnb;
//        issue DMA x(ch+2) -> Xb[ch&1]        (in flight across B(ch+1))
//   BAR
// -----------------------------------------------------------------------------
__global__ __launch_bounds__(256, 1) void fused_mingru(
    const float* __restrict__ x, const float* __restrict__ prevh,
    const unsigned short* __restrict__ wfrag, const float* __restrict__ bp,
    float* __restrict__ out, float* __restrict__ nexth)
{
    __shared__ __align__(16) unsigned char Xb[2][CH*512];   // 2 x 32 KB f32 x
    __shared__ __align__(16) unsigned char xnb[CH*256];     // 16 KB bf16 xn
    __shared__ __align__(16) float2 cvb[CH][DD];            // 64 KB c,v

    const int tid  = threadIdx.x;
    const int w    = tid >> 6;
    const int lane = tid & 63;
    const int l15  = lane & 15;
    const int lhi  = lane >> 4;

    // ---- W fragments (bf16, pre-packed) + folded bias ----
    short8 wfr[4][4];
    #pragma unroll
    for (int ni = 0; ni < 4; ++ni)
        #pragma unroll
        for (int kt = 0; kt < 4; ++kt)
            wfr[ni][kt] = *(const short8*)(wfrag + (size_t)(((w*4+ni)*4+kt)*64 + lane)*8);
    float bs[4];
    #pragma unroll
    for (int ni = 0; ni < 4; ++ni) {
        const int nt = (ni < 2) ? (2*w + ni) : (8 + 2*w + (ni - 2));
        bs[ni] = bp[nt*16 + l15];
    }

    const size_t rowstride = (size_t)TT * DD;               // 2048
    const size_t base_bt   = ((size_t)(blockIdx.x >> 4) * SS * TT + (blockIdx.x & 15)) * DD;

    float h = 0.0f;
    if (tid < 128) h = prevh[(size_t)blockIdx.x * 128 + tid];

    // ---- DMA stage: 32 instrs cover 64 rows; w2 does j=0..15, w3 j=16..31.
    // Stored chunk cc of row r holds x chunk (cc ^ (r&7))  [source pre-swizzle]
    auto stageX = [&](int ch, int buf) {
        const int j0 = (w == 2) ? 0 : 16;
        #pragma unroll
        for (int jj = 0; jj < 16; ++jj) {
            const int j  = j0 + jj;
            const int r  = 2*j + (lane >> 5);
            const int cc = lane & 31;
            const float* src = x + base_bt + (size_t)(ch*CH + r)*rowstride
                                 + ((cc ^ (r & 7)) << 2);
            dma16(src, &Xb[buf][j*1024]);
        }
    };

    // ---- LN (w23): two-pass from Xb[buf], write bf16 xn (swizzled) ----
    const int tid2 = tid & 127;
    const int r_a  = tid2 >> 1;          // row 0..63
    const int half = tid2 & 1;           // half-row (64 floats)
    auto phaseLN = [&](int buf) {
        const unsigned char* xr = Xb[buf] + r_a*512;
        const int rx = r_a & 7;
        float s1 = 0.f, s2 = 0.f;
        #pragma unroll
        for (int q = 0; q < 16; ++q) {
            const int cc = (half*16 + q) ^ rx;
            const f32x4 a = *(const f32x4*)(xr + cc*16);
            s1 += a.x + a.y + a.z + a.w;
            s2 += a.x*a.x + a.y*a.y + a.z*a.z + a.w*a.w;
        }
        s1 += __shfl_xor(s1, 1);
        s2 += __shfl_xor(s2, 1);
        const float mu = s1 * (1.0f/128.0f);
        const float rs = rsqrtf(s2 * (1.0f/128.0f) - mu*mu + LN_EPS);
        unsigned char* row = xnb + r_a*256;
        #pragma unroll
        for (int q2 = 0; q2 < 8; ++q2) {
            const int c0 = half*16 + 2*q2;
            const f32x4 a = *(const f32x4*)(xr + ((c0    ^ rx) << 4));
            const f32x4 b = *(const f32x4*)(xr + (((c0+1) ^ rx) << 4));
            const float fe[8] = {a.x,a.y,a.z,a.w, b.x,b.y,b.z,b.w};
            short8 sv;
            #pragma unroll
            for (int e = 0; e < 8; ++e)
                sv[e] = (short)f2bf((fe[e] - mu) * rs);
            const int ci = half*8 + q2;                      // 16B chunk 0..15
            *(short8*)(row + ((ci ^ rx) << 4)) = sv;
        }
    };

    // ---- B: all 4 waves, MFMA + activation -> cvb ----
    auto phaseB = [&]() {
        #pragma unroll
        for (int mt = 0; mt < 4; ++mt) {
            const unsigned char* rowp = xnb + (mt*16 + l15)*256;
            short8 af[4];
            #pragma unroll
            for (int kt = 0; kt < 4; ++kt) {
                const int c = (kt << 2) | lhi;
                af[kt] = *(const short8*)(rowp + ((c ^ (l15 & 7)) << 4));
            }
            f32x4 ag[2] = {(f32x4)(0.f), (f32x4)(0.f)};
            f32x4 ah[2] = {(f32x4)(0.f), (f32x4)(0.f)};
            #pragma unroll
            for (int kt = 0; kt < 4; ++kt) {
                #pragma unroll
                for (int i = 0; i < 2; ++i) {
                    ag[i] = __builtin_amdgcn_mfma_f32_16x16x32_bf16(af[kt], wfr[i][kt],   ag[i], 0, 0, 0);
                    ah[i] = __builtin_amdgcn_mfma_f32_16x16x32_bf16(af[kt], wfr[2+i][kt], ah[i], 0, 0, 0);
                }
            }
            #pragma unroll
            for (int i = 0; i < 2; ++i) {
                const int d = (2*w + i)*16 + l15;            // 0..127
                #pragma unroll
                for (int j = 0; j < 4; ++j) {
                    const int ls = mt*16 + lhi*4 + j;
                    const float g  = ag[i][j] + bs[i];
                    const float hh = ah[i][j] + bs[2+i];
                    const float c  = 1.0f / (1.0f + __expf(g));
                    const float ga = (hh >= 0.0f) ? (hh + 0.5f)
                                                  : (1.0f / (1.0f + __expf(-hh)));
                    cvb[ls][d] = make_float2(c, (1.0f - c) * ga);
                }
            }
        }
    };

    // ---- C (w01): sequential scan of the chunk ----
    auto phaseC = [&](int ch) {
        float* op = out + base_bt + (size_t)ch * CH * rowstride + tid;
        #pragma unroll 16
        for (int ls = 0; ls < CH; ++ls) {
            const float2 cv = cvb[ls][tid];
            h = fmaf(cv.x, h, cv.y);
            op[(size_t)ls * rowstride] = h;
        }
    };

    // ---- prologue: stage x(0), LN(0), stage x(1) ----
    if (w >= 2) {
        stageX(0, 0);
        asm volatile("s_waitcnt vmcnt(0)" ::: "memory");
        phaseLN(0);
        stageX(1, 1);
    }
    BAR();

    for (int ch = 0; ch < NCH; ++ch) {
        phaseB();
        BAR();
        if (w < 2) {
            phaseC(ch);
        } else if (ch + 1 < NCH) {
            asm volatile("s_waitcnt vmcnt(0)" ::: "memory");  // x(ch+1) landed
            phaseLN((ch + 1) & 1);
            if (ch + 2 < NCH) stageX(ch + 2, ch & 1);
        }
        BAR();
    }
    if (tid < 128) nexth[(size_t)blockIdx.x * 128 + tid] = h;
}

extern "C" void kernel_launch(void* const* d_in, const int* in_sizes, int n_in,
                              void* d_out, int out_size, void* d_ws, size_t ws_size,
                              hipStream_t stream) {
    const float* x     = (const float*)d_in[0];
    const float* prevh = (const float*)d_in[1];
    const float* gamma = (const float*)d_in[2];
    const float* beta  = (const float*)d_in[3];
    const float* W     = (const float*)d_in[4];
    const float* bias  = (const float*)d_in[5];

    float* out   = (float*)d_out;
    float* nexth = out + (size_t)BB*SS*TT*DD;              // 16777216

    unsigned short* wf  = (unsigned short*)d_ws;           // 64 KB fragments
    float*          bpf = (float*)((char*)d_ws + 65536);   // 1 KB folded bias

    k0_pack<<<129, 256, 0, stream>>>(W, gamma, beta, bias, wf, bpf);
    fused_mingru<<<BB*TT, 256, 0, stream>>>(x, prevh, wf, bpf, out, nexth);
}

// Round 7
// 53.244 us; speedup vs baseline: 2.5017x; 1.1298x over previous
//
#include <hip/hip_runtime.h>
#include <hip/hip_bf16.h>
#include <stdint.h>

// Problem constants
#define BB 16
#define SS 512
#define TT 16
#define DD 128
#define CH 32                 // s-chunk per pipeline stage
#define NCH (SS/CH)           // 16
#define LN_EPS 1e-5f

typedef __attribute__((ext_vector_type(8))) short short8;
typedef __attribute__((ext_vector_type(4))) float f32x4;

static __device__ __forceinline__ unsigned short f2bf(float f) {
    unsigned int u = __float_as_uint(f);
    u += 0x7fffu + ((u >> 16) & 1u);   // round-to-nearest-even
    return (unsigned short)(u >> 16);
}

// async global->LDS DMA, 16B per lane, LDS dest = uniform base + lane*16
static __device__ __forceinline__ void dma16(const float* g, unsigned char* l) {
    __builtin_amdgcn_global_load_lds(
        (const __attribute__((address_space(1))) unsigned int*)g,
        (__attribute__((address_space(3))) unsigned int*)l, 16, 0, 0);
}

// LDS-ordering barrier (does NOT drain vmcnt; DMA stays in flight across it)
#define BAR() do {                                            \
    asm volatile("s_waitcnt lgkmcnt(0)" ::: "memory");        \
    __builtin_amdgcn_s_barrier();                             \
    asm volatile("" ::: "memory");                            \
} while (0)

// -----------------------------------------------------------------------------
// k0: fold LN affine into the GEMM and pack fragments.
//   W'[k,col] = gamma[k] * W[k,col]   (bf16, MFMA B-fragment order)
//   b'[col]   = bias[col] + sum_k beta[k] * W[k,col]   (f32)
// -----------------------------------------------------------------------------
__global__ __launch_bounds__(256) void k0_pack(
    const float* __restrict__ W, const float* __restrict__ gamma,
    const float* __restrict__ beta, const float* __restrict__ bias,
    unsigned short* __restrict__ wf, float* __restrict__ bp)
{
    if (blockIdx.x < 128) {
        const int id   = blockIdx.x * 256 + threadIdx.x;   // 0..32767
        const int j    = id & 7;
        const int lane = (id >> 3) & 63;
        const int kt   = (id >> 9) & 3;
        const int ni   = (id >> 11) & 3;
        const int w    = (id >> 13) & 3;
        const int nt   = (ni < 2) ? (2*w + ni) : (8 + 2*w + (ni - 2));
        const int col  = nt*16 + (lane & 15);
        const int k    = kt*32 + (lane >> 4)*8 + j;
        wf[id] = f2bf(gamma[k] * W[(size_t)k*256 + col]);
    } else {
        const int col = threadIdx.x;                        // 0..255
        float s = bias[col];
        #pragma unroll 8
        for (int k = 0; k < 128; ++k)
            s = fmaf(beta[k], W[(size_t)k*256 + col], s);
        bp[col] = s;
    }
}

// -----------------------------------------------------------------------------
// Fused kernel, one block per (b,t), 8 waves (2/SIMD), 3-stage pipeline with
// ONE barrier per stage:
//   w0-1 : scan chunk st-2 from cvb[(st-2)&1], write out
//   w4-7 : GEMM+act chunk st-1: xn[(st-1)&1] -> cvb[(st-1)&1]
//   w2-3 : vmcnt(0); LN chunk st: Xb[st&1] -> xn[st&1]; DMA x(st+1)->Xb[~]
// -----------------------------------------------------------------------------
__global__ __launch_bounds__(512, 2) void fused_mingru(
    const float* __restrict__ x, const float* __restrict__ prevh,
    const unsigned short* __restrict__ wfrag, const float* __restrict__ bp,
    float* __restrict__ out, float* __restrict__ nexth)
{
    __shared__ __align__(16) unsigned char Xb[2][CH*512];   // 2 x 16 KB f32 x
    __shared__ __align__(16) unsigned char xnb[2][CH*256];  // 2 x 8 KB bf16 xn
    __shared__ __align__(16) float2 cvb[2][CH][DD];         // 2 x 32 KB c,v

    const int tid  = threadIdx.x;
    const int w    = tid >> 6;           // 0..7
    const int lane = tid & 63;
    const int l15  = lane & 15;
    const int lhi  = lane >> 4;

    const size_t rowstride = (size_t)TT * DD;               // 2048
    const size_t base_bt   = ((size_t)(blockIdx.x >> 4) * SS * TT + (blockIdx.x & 15)) * DD;

    // ---- GEMM waves (w4-7): W fragments + folded bias ----
    const int wid2 = w - 4;              // 0..3 for GEMM waves
    short8 wfr[4][4];
    float  bs[4];
    if (w >= 4) {
        #pragma unroll
        for (int ni = 0; ni < 4; ++ni)
            #pragma unroll
            for (int kt = 0; kt < 4; ++kt)
                wfr[ni][kt] = *(const short8*)(wfrag + (size_t)(((wid2*4+ni)*4+kt)*64 + lane)*8);
        #pragma unroll
        for (int ni = 0; ni < 4; ++ni) {
            const int nt = (ni < 2) ? (2*wid2 + ni) : (8 + 2*wid2 + (ni - 2));
            bs[ni] = bp[nt*16 + l15];
        }
    }

    // ---- scan waves (w0-1): running state ----
    float h = 0.0f;
    if (tid < 128) h = prevh[(size_t)blockIdx.x * 128 + tid];

    // ---- LN waves (w2-3): row/quarter assignment ----
    const int tid2 = tid & 127;          // 0..127 for w2-3
    const int r_a  = tid2 >> 2;          // row 0..31
    const int q_a  = tid2 & 3;           // quarter of the row (32 floats)
    const int rx   = r_a & 7;

    // DMA stage: 16 instrs (8 per wave) cover 32 rows x 512 B.
    // Stored slot cc of row r holds logical f32-chunk (cc ^ (r&7)).
    auto stageX = [&](int ch) {
        unsigned char* dst = Xb[ch & 1];
        const int j0 = (w == 2) ? 0 : 8;
        #pragma unroll
        for (int jj = 0; jj < 8; ++jj) {
            const int j  = j0 + jj;
            const int r  = 2*j + (lane >> 5);
            const int cc = lane & 31;
            const float* src = x + base_bt + (size_t)(ch*CH + r)*rowstride
                                 + (((cc ^ (r & 7)) << 2));
            dma16(src, dst + j*1024);
        }
    };

    // LN chunk st: Xb[st&1] -> xnb[st&1]  (4 threads per row)
    auto phaseLN = [&](int st) {
        const unsigned char* xr = Xb[st & 1] + r_a*512;
        f32x4 vv[8];
        #pragma unroll
        for (int k = 0; k < 8; ++k)
            vv[k] = *(const f32x4*)(xr + (((q_a*8 + k) ^ rx) << 4));
        float s1 = 0.f, s2 = 0.f;
        #pragma unroll
        for (int k = 0; k < 8; ++k) {
            s1 += vv[k].x + vv[k].y + vv[k].z + vv[k].w;
            s2 += vv[k].x*vv[k].x + vv[k].y*vv[k].y + vv[k].z*vv[k].z + vv[k].w*vv[k].w;
        }
        s1 += __shfl_xor(s1, 1); s2 += __shfl_xor(s2, 1);
        s1 += __shfl_xor(s1, 2); s2 += __shfl_xor(s2, 2);
        const float mu = s1 * (1.0f/128.0f);
        const float rs = rsqrtf(s2 * (1.0f/128.0f) - mu*mu + LN_EPS);
        unsigned char* row = xnb[st & 1] + r_a*256;
        #pragma unroll
        for (int m = 0; m < 4; ++m) {
            const f32x4 a = vv[2*m], b = vv[2*m+1];
            const float fe[8] = {a.x,a.y,a.z,a.w, b.x,b.y,b.z,b.w};
            short8 sv;
            #pragma unroll
            for (int e = 0; e < 8; ++e)
                sv[e] = (short)f2bf((fe[e] - mu) * rs);
            *(short8*)(row + (((q_a*4 + m) ^ rx) << 4)) = sv;
        }
    };

    // GEMM + activation chunk st: xnb[st&1] -> cvb[st&1]
    auto phaseG = [&](int st) {
        const int bx = st & 1;
        #pragma unroll
        for (int mt = 0; mt < 2; ++mt) {
            const unsigned char* rowp = xnb[bx] + (mt*16 + l15)*256;
            short8 af[4];
            #pragma unroll
            for (int kt = 0; kt < 4; ++kt) {
                const int c = (kt << 2) | lhi;
                af[kt] = *(const short8*)(rowp + ((c ^ (l15 & 7)) << 4));
            }
            f32x4 ag[2] = {(f32x4)(0.f), (f32x4)(0.f)};
            f32x4 ah[2] = {(f32x4)(0.f), (f32x4)(0.f)};
            #pragma unroll
            for (int kt = 0; kt < 4; ++kt) {
                #pragma unroll
                for (int i = 0; i < 2; ++i) {
                    ag[i] = __builtin_amdgcn_mfma_f32_16x16x32_bf16(af[kt], wfr[i][kt],   ag[i], 0, 0, 0);
                    ah[i] = __builtin_amdgcn_mfma_f32_16x16x32_bf16(af[kt], wfr[2+i][kt], ah[i], 0, 0, 0);
                }
            }
            #pragma unroll
            for (int i = 0; i < 2; ++i) {
                const int d = (2*wid2 + i)*16 + l15;         // 0..127
                #pragma unroll
                for (int j = 0; j < 4; ++j) {
                    const int ls = mt*16 + lhi*4 + j;
                    const float g  = ag[i][j] + bs[i];
                    const float hh = ah[i][j] + bs[2+i];
                    const float c  = 1.0f / (1.0f + __expf(g));
                    const float ga = (hh >= 0.0f) ? (hh + 0.5f)
                                                  : (1.0f / (1.0f + __expf(-hh)));
                    cvb[bx][ls][d] = make_float2(c, (1.0f - c) * ga);
                }
            }
        }
    };

    // scan chunk st (w0-1): cvb[st&1] -> out
    auto phaseC = [&](int st) {
        const int bc = st & 1;
        float* op = out + base_bt + (size_t)st * CH * rowstride + tid;
        #pragma unroll 8
        for (int ls = 0; ls < CH; ++ls) {
            const float2 cv = cvb[bc][ls][tid];
            h = fmaf(cv.x, h, cv.y);
            op[(size_t)ls * rowstride] = h;
        }
    };

    // ---- prologue: stage x(0) (w2-3 only; consumed by same waves at st=0) ----
    if (w == 2 || w == 3) stageX(0);

    // ---- pipeline: 18 stages, one barrier each ----
    for (int st = 0; st <= NCH + 1; ++st) {
        if (w >= 4) {
            if (st >= 1 && st <= NCH) phaseG(st - 1);
        } else if (w >= 2) {
            if (st < NCH) {
                asm volatile("s_waitcnt vmcnt(0)" ::: "memory");  // x(st) landed
                phaseLN(st);
                if (st + 1 < NCH) stageX(st + 1);
            }
        } else {
            if (st >= 2) phaseC(st - 2);
        }
        BAR();
    }
    if (tid < 128) nexth[(size_t)blockIdx.x * 128 + tid] = h;
}

extern "C" void kernel_launch(void* const* d_in, const int* in_sizes, int n_in,
                              void* d_out, int out_size, void* d_ws, size_t ws_size,
                              hipStream_t stream) {
    const float* x     = (const float*)d_in[0];
    const float* prevh = (const float*)d_in[1];
    const float* gamma = (const float*)d_in[2];
    const float* beta  = (const float*)d_in[3];
    const float* W     = (const float*)d_in[4];
    const float* bias  = (const float*)d_in[5];

    float* out   = (float*)d_out;
    float* nexth = out + (size_t)BB*SS*TT*DD;              // 16777216

    unsigned short* wf  = (unsigned short*)d_ws;           // 64 KB fragments
    float*          bpf = (float*)((char*)d_ws + 65536);   // 1 KB folded bias

    k0_pack<<<129, 256, 0, stream>>>(W, gamma, beta, bias, wf, bpf);
    fused_mingru<<<BB*TT, 512, 0, stream>>>(x, prevh, wf, bpf, out, nexth);
}

// Round 8
// 48.017 us; speedup vs baseline: 2.7740x; 1.1089x over previous
//
#include <hip/hip_runtime.h>
#include <hip/hip_bf16.h>
#include <stdint.h>

// Problem constants
#define BB 16
#define SS 512
#define TT 16
#define DD 128
#define CH 32                 // s-chunk per pipeline stage
#define NCH (SS/CH)           // 16
#define LN_EPS 1e-5f

typedef __attribute__((ext_vector_type(8))) short short8;
typedef __attribute__((ext_vector_type(4))) float f32x4;

static __device__ __forceinline__ unsigned short f2bf(float f) {
    unsigned int u = __float_as_uint(f);
    u += 0x7fffu + ((u >> 16) & 1u);   // round-to-nearest-even
    return (unsigned short)(u >> 16);
}

// async global->LDS DMA, 16B per lane, LDS dest = uniform base + lane*16
static __device__ __forceinline__ void dma16(const float* g, unsigned char* l) {
    __builtin_amdgcn_global_load_lds(
        (const __attribute__((address_space(1))) unsigned int*)g,
        (__attribute__((address_space(3))) unsigned int*)l, 16, 0, 0);
}

// LDS-ordering barrier (does NOT drain vmcnt; DMA stays in flight across it)
#define BAR() do {                                            \
    asm volatile("s_waitcnt lgkmcnt(0)" ::: "memory");        \
    __builtin_amdgcn_s_barrier();                             \
    asm volatile("" ::: "memory");                            \
} while (0)

// -----------------------------------------------------------------------------
// k0: fold LN affine into the GEMM and pack fragments, keyed by n-tile:
//   flat = ((nt*4 + kt)*64 + lane)*8 + j ; nt in [0,16)
//   col = nt*16 + (lane&15) ; k = kt*32 + (lane>>4)*8 + j
//   W'[k,col] = gamma[k] * W[k,col]  (bf16)
//   b'[col]   = bias[col] + sum_k beta[k] * W[k,col]  (f32)
// -----------------------------------------------------------------------------
__global__ __launch_bounds__(256) void k0_pack(
    const float* __restrict__ W, const float* __restrict__ gamma,
    const float* __restrict__ beta, const float* __restrict__ bias,
    unsigned short* __restrict__ wf, float* __restrict__ bp)
{
    if (blockIdx.x < 128) {
        const int id   = blockIdx.x * 256 + threadIdx.x;   // 0..32767
        const int j    = id & 7;
        const int lane = (id >> 3) & 63;
        const int kt   = (id >> 9) & 3;
        const int nt   = (id >> 11) & 15;
        const int col  = nt*16 + (lane & 15);
        const int k    = kt*32 + (lane >> 4)*8 + j;
        wf[id] = f2bf(gamma[k] * W[(size_t)k*256 + col]);
    } else {
        const int col = threadIdx.x;                        // 0..255
        float s = bias[col];
        #pragma unroll 8
        for (int k = 0; k < 128; ++k)
            s = fmaf(beta[k], W[(size_t)k*256 + col], s);
        bp[col] = s;
    }
}

// -----------------------------------------------------------------------------
// Fused kernel, one block per (b,t), 12 waves (3/SIMD), 3-stage pipeline,
// one barrier per stage:
//   w0-1  : scan chunk st-2 from cvb[(st-2)&1], write out
//   w4-11 : GEMM+act chunk st-1 (each wave: 1 gate + 1 hidden n-tile)
//   w2-3  : vmcnt(0); LN chunk st: Xb[st&1] -> xn[st&1]; DMA x(st+1)
// -----------------------------------------------------------------------------
__global__ __launch_bounds__(768, 1) void fused_mingru(
    const float* __restrict__ x, const float* __restrict__ prevh,
    const unsigned short* __restrict__ wfrag, const float* __restrict__ bp,
    float* __restrict__ out, float* __restrict__ nexth)
{
    __shared__ __align__(16) unsigned char Xb[2][CH*512];   // 2 x 16 KB f32 x
    __shared__ __align__(16) unsigned char xnb[2][CH*256];  // 2 x 8 KB bf16 xn
    __shared__ __align__(16) float2 cvb[2][CH][DD];         // 2 x 32 KB c,v

    const int tid  = threadIdx.x;
    const int w    = tid >> 6;           // 0..11
    const int lane = tid & 63;
    const int l15  = lane & 15;
    const int lhi  = lane >> 4;

    const size_t rowstride = (size_t)TT * DD;               // 2048
    const size_t base_bt   = ((size_t)(blockIdx.x >> 4) * SS * TT + (blockIdx.x & 15)) * DD;

    // ---- GEMM waves (w4-11): 1 gate + 1 hidden n-tile each ----
    const int gw = w - 4;                // 0..7 for GEMM waves
    short8 wfr[2][4];
    float  bs2[2];
    if (w >= 4) {
        #pragma unroll
        for (int ni = 0; ni < 2; ++ni) {
            const int nt = ni ? (8 + gw) : gw;
            #pragma unroll
            for (int kt = 0; kt < 4; ++kt)
                wfr[ni][kt] = *(const short8*)(wfrag + (size_t)(((nt*4+kt)*64 + lane)*8));
        }
        bs2[0] = bp[gw*16 + l15];        // gate col
        bs2[1] = bp[128 + gw*16 + l15];  // hidden col
    }

    // ---- scan waves (w0-1): running state ----
    float h = 0.0f;
    if (tid < 128) h = prevh[(size_t)blockIdx.x * 128 + tid];

    // ---- LN waves (w2-3): row/quarter assignment ----
    const int tid2 = tid & 127;          // 0..127 for w2-3
    const int r_a  = tid2 >> 2;          // row 0..31
    const int q_a  = tid2 & 3;           // quarter of the row (32 floats)
    const int rx   = r_a & 7;

    // DMA stage: 16 instrs (8 per wave) cover 32 rows x 512 B.
    // Stored slot cc of row r holds logical f32-chunk (cc ^ (r&7)).
    auto stageX = [&](int ch) {
        unsigned char* dst = Xb[ch & 1];
        const int j0 = (w == 2) ? 0 : 8;
        #pragma unroll
        for (int jj = 0; jj < 8; ++jj) {
            const int j  = j0 + jj;
            const int r  = 2*j + (lane >> 5);
            const int cc = lane & 31;
            const float* src = x + base_bt + (size_t)(ch*CH + r)*rowstride
                                 + (((cc ^ (r & 7)) << 2));
            dma16(src, dst + j*1024);
        }
    };

    // LN chunk st: Xb[st&1] -> xnb[st&1]  (4 threads per row)
    auto phaseLN = [&](int st) {
        const unsigned char* xr = Xb[st & 1] + r_a*512;
        f32x4 vv[8];
        #pragma unroll
        for (int k = 0; k < 8; ++k)
            vv[k] = *(const f32x4*)(xr + (((q_a*8 + k) ^ rx) << 4));
        float s1 = 0.f, s2 = 0.f;
        #pragma unroll
        for (int k = 0; k < 8; ++k) {
            s1 += vv[k].x + vv[k].y + vv[k].z + vv[k].w;
            s2 += vv[k].x*vv[k].x + vv[k].y*vv[k].y + vv[k].z*vv[k].z + vv[k].w*vv[k].w;
        }
        s1 += __shfl_xor(s1, 1); s2 += __shfl_xor(s2, 1);
        s1 += __shfl_xor(s1, 2); s2 += __shfl_xor(s2, 2);
        const float mu = s1 * (1.0f/128.0f);
        const float rs = rsqrtf(s2 * (1.0f/128.0f) - mu*mu + LN_EPS);
        unsigned char* row = xnb[st & 1] + r_a*256;
        #pragma unroll
        for (int m = 0; m < 4; ++m) {
            const f32x4 a = vv[2*m], b = vv[2*m+1];
            const float fe[8] = {a.x,a.y,a.z,a.w, b.x,b.y,b.z,b.w};
            short8 sv;
            #pragma unroll
            for (int e = 0; e < 8; ++e)
                sv[e] = (short)f2bf((fe[e] - mu) * rs);
            *(short8*)(row + (((q_a*4 + m) ^ rx) << 4)) = sv;
        }
    };

    // GEMM + activation chunk st: xnb[st&1] -> cvb[st&1]
    auto phaseG = [&](int st) {
        const int bx = st & 1;
        #pragma unroll
        for (int mt = 0; mt < 2; ++mt) {
            const unsigned char* rowp = xnb[bx] + (mt*16 + l15)*256;
            short8 af[4];
            #pragma unroll
            for (int kt = 0; kt < 4; ++kt) {
                const int c = (kt << 2) | lhi;
                af[kt] = *(const short8*)(rowp + ((c ^ (l15 & 7)) << 4));
            }
            f32x4 ag = (f32x4)(0.f), ah = (f32x4)(0.f);
            #pragma unroll
            for (int kt = 0; kt < 4; ++kt) {
                ag = __builtin_amdgcn_mfma_f32_16x16x32_bf16(af[kt], wfr[0][kt], ag, 0, 0, 0);
                ah = __builtin_amdgcn_mfma_f32_16x16x32_bf16(af[kt], wfr[1][kt], ah, 0, 0, 0);
            }
            const int d = gw*16 + l15;                       // 0..127
            #pragma unroll
            for (int j = 0; j < 4; ++j) {
                const int ls = mt*16 + lhi*4 + j;
                const float g  = ag[j] + bs2[0];
                const float hh = ah[j] + bs2[1];
                const float c  = 1.0f / (1.0f + __expf(g));
                const float ga = (hh >= 0.0f) ? (hh + 0.5f)
                                              : (1.0f / (1.0f + __expf(-hh)));
                cvb[bx][ls][d] = make_float2(c, (1.0f - c) * ga);
            }
        }
    };

    // scan chunk st (w0-1): cvb[st&1] -> out
    auto phaseC = [&](int st) {
        const int bc = st & 1;
        float* op = out + base_bt + (size_t)st * CH * rowstride + tid;
        #pragma unroll 8
        for (int ls = 0; ls < CH; ++ls) {
            const float2 cv = cvb[bc][ls][tid];
            h = fmaf(cv.x, h, cv.y);
            op[(size_t)ls * rowstride] = h;
        }
    };

    // ---- prologue: stage x(0) (w2-3 only; consumed by same waves at st=0) ----
    if (w == 2 || w == 3) stageX(0);

    // ---- pipeline: NCH+2 stages, one barrier each ----
    for (int st = 0; st <= NCH + 1; ++st) {
        if (w >= 4) {
            if (st >= 1 && st <= NCH) phaseG(st - 1);
        } else if (w >= 2) {
            if (st < NCH) {
                asm volatile("s_waitcnt vmcnt(0)" ::: "memory");  // x(st) landed
                phaseLN(st);
                if (st + 1 < NCH) stageX(st + 1);
            }
        } else {
            if (st >= 2) phaseC(st - 2);
        }
        BAR();
    }
    if (tid < 128) nexth[(size_t)blockIdx.x * 128 + tid] = h;
}

extern "C" void kernel_launch(void* const* d_in, const int* in_sizes, int n_in,
                              void* d_out, int out_size, void* d_ws, size_t ws_size,
                              hipStream_t stream) {
    const float* x     = (const float*)d_in[0];
    const float* prevh = (const float*)d_in[1];
    const float* gamma = (const float*)d_in[2];
    const float* beta  = (const float*)d_in[3];
    const float* W     = (const float*)d_in[4];
    const float* bias  = (const float*)d_in[5];

    float* out   = (float*)d_out;
    float* nexth = out + (size_t)BB*SS*TT*DD;              // 16777216

    unsigned short* wf  = (unsigned short*)d_ws;           // 64 KB fragments
    float*          bpf = (float*)((char*)d_ws + 65536);   // 1 KB folded bias

    k0_pack<<<129, 256, 0, stream>>>(W, gamma, beta, bias, wf, bpf);
    fused_mingru<<<BB*TT, 768, 0, stream>>>(x, prevh, wf, bpf, out, nexth);
}

// Round 9
// 47.587 us; speedup vs baseline: 2.7990x; 1.0090x over previous
//
#include <hip/hip_runtime.h>
#include <hip/hip_bf16.h>
#include <stdint.h>

// Problem constants
#define BB 16
#define SS 512
#define TT 16
#define DD 128
#define CH 32                 // s-chunk per pipeline stage
#define NCH (SS/CH)           // 16
#define LN_EPS 1e-5f

typedef __attribute__((ext_vector_type(8))) short short8;
typedef __attribute__((ext_vector_type(4))) float f32x4;

static __device__ __forceinline__ unsigned short f2bf(float f) {
    unsigned int u = __float_as_uint(f);
    u += 0x7fffu + ((u >> 16) & 1u);   // round-to-nearest-even
    return (unsigned short)(u >> 16);
}

// HW packed f32->bf16 (RNE): dst.lo = src0, dst.hi = src1
static __device__ __forceinline__ uint32_t cvt_pk_bf16(float lo, float hi) {
    uint32_t r;
    asm("v_cvt_pk_bf16_f32 %0, %1, %2" : "=v"(r) : "v"(lo), "v"(hi));
    return r;
}

// async global->LDS DMA, 16B per lane, LDS dest = uniform base + lane*16
static __device__ __forceinline__ void dma16(const float* g, unsigned char* l) {
    __builtin_amdgcn_global_load_lds(
        (const __attribute__((address_space(1))) unsigned int*)g,
        (__attribute__((address_space(3))) unsigned int*)l, 16, 0, 0);
}

// LDS-ordering barrier (does NOT drain vmcnt; DMA stays in flight across it)
#define BAR() do {                                            \
    asm volatile("s_waitcnt lgkmcnt(0)" ::: "memory");        \
    __builtin_amdgcn_s_barrier();                             \
    asm volatile("" ::: "memory");                            \
} while (0)

// -----------------------------------------------------------------------------
// k0: fold LN affine into the GEMM and pack fragments, keyed by n-tile:
//   flat = ((nt*4 + kt)*64 + lane)*8 + j ; nt in [0,16)
//   col = nt*16 + (lane&15) ; k = kt*32 + (lane>>4)*8 + j
//   W'[k,col] = gamma[k] * W[k,col]  (bf16)
//   b'[col]   = bias[col] + sum_k beta[k] * W[k,col]  (f32)
// -----------------------------------------------------------------------------
__global__ __launch_bounds__(256) void k0_pack(
    const float* __restrict__ W, const float* __restrict__ gamma,
    const float* __restrict__ beta, const float* __restrict__ bias,
    unsigned short* __restrict__ wf, float* __restrict__ bp)
{
    if (blockIdx.x < 128) {
        const int id   = blockIdx.x * 256 + threadIdx.x;   // 0..32767
        const int j    = id & 7;
        const int lane = (id >> 3) & 63;
        const int kt   = (id >> 9) & 3;
        const int nt   = (id >> 11) & 15;
        const int col  = nt*16 + (lane & 15);
        const int k    = kt*32 + (lane >> 4)*8 + j;
        wf[id] = f2bf(gamma[k] * W[(size_t)k*256 + col]);
    } else {
        const int col = threadIdx.x;                        // 0..255
        float s = bias[col];
        #pragma unroll 8
        for (int k = 0; k < 128; ++k)
            s = fmaf(beta[k], W[(size_t)k*256 + col], s);
        bp[col] = s;
    }
}

// -----------------------------------------------------------------------------
// Fused kernel, one block per (b,t), 12 waves (3/SIMD), 3-stage pipeline,
// one barrier per stage:
//   w0-1  : scan chunk st-2 from cvb[(st-2)&1], write out
//   w4-11 : GEMM+act chunk st-1 (each wave: 1 gate + 1 hidden n-tile)
//   w2-3  : vmcnt(8) [x(st) landed, x(st+1) in flight]; LN Xb[st%3]->xn[st&1];
//           issue DMA x(st+2) -> Xb[(st+2)%3]   (2-stage prefetch distance)
// -----------------------------------------------------------------------------
__global__ __launch_bounds__(768, 1) void fused_mingru(
    const float* __restrict__ x, const float* __restrict__ prevh,
    const unsigned short* __restrict__ wfrag, const float* __restrict__ bp,
    float* __restrict__ out, float* __restrict__ nexth)
{
    __shared__ __align__(16) unsigned char Xb[3][CH*512];   // 3 x 16 KB f32 x
    __shared__ __align__(16) unsigned char xnb[2][CH*256];  // 2 x 8 KB bf16 xn
    __shared__ __align__(16) float2 cvb[2][CH][DD];         // 2 x 32 KB c,v

    const int tid  = threadIdx.x;
    const int w    = tid >> 6;           // 0..11
    const int lane = tid & 63;
    const int l15  = lane & 15;
    const int lhi  = lane >> 4;

    const size_t rowstride = (size_t)TT * DD;               // 2048
    const size_t base_bt   = ((size_t)(blockIdx.x >> 4) * SS * TT + (blockIdx.x & 15)) * DD;

    // ---- GEMM waves (w4-11): 1 gate + 1 hidden n-tile each ----
    const int gw = w - 4;                // 0..7 for GEMM waves
    short8 wfr[2][4];
    float  bs2[2];
    if (w >= 4) {
        #pragma unroll
        for (int ni = 0; ni < 2; ++ni) {
            const int nt = ni ? (8 + gw) : gw;
            #pragma unroll
            for (int kt = 0; kt < 4; ++kt)
                wfr[ni][kt] = *(const short8*)(wfrag + (size_t)(((nt*4+kt)*64 + lane)*8));
        }
        bs2[0] = bp[gw*16 + l15];        // gate col
        bs2[1] = bp[128 + gw*16 + l15];  // hidden col
    }

    // ---- scan waves (w0-1): running state ----
    float h = 0.0f;
    if (tid < 128) h = prevh[(size_t)blockIdx.x * 128 + tid];

    // ---- LN waves (w2-3): row/quarter assignment ----
    const int tid2 = tid & 127;          // 0..127 for w2-3
    const int r_a  = tid2 >> 2;          // row 0..31
    const int q_a  = tid2 & 3;           // quarter of the row (32 floats)
    const int rx   = r_a & 7;

    // DMA stage: 16 instrs (8 per wave) cover 32 rows x 512 B.
    // Stored slot cc of row r holds logical f32-chunk (cc ^ (r&7)).
    auto stageX = [&](int ch) {
        unsigned char* dst = Xb[ch % 3];
        const int j0 = (w == 2) ? 0 : 8;
        #pragma unroll
        for (int jj = 0; jj < 8; ++jj) {
            const int j  = j0 + jj;
            const int r  = 2*j + (lane >> 5);
            const int cc = lane & 31;
            const float* src = x + base_bt + (size_t)(ch*CH + r)*rowstride
                                 + (((cc ^ (r & 7)) << 2));
            dma16(src, dst + j*1024);
        }
    };

    // LN chunk st: Xb[st%3] -> xnb[st&1]  (4 threads per row)
    auto phaseLN = [&](int st) {
        const unsigned char* xr = Xb[st % 3] + r_a*512;
        f32x4 vv[8];
        #pragma unroll
        for (int k = 0; k < 8; ++k)
            vv[k] = *(const f32x4*)(xr + (((q_a*8 + k) ^ rx) << 4));
        float s1 = 0.f, s2 = 0.f;
        #pragma unroll
        for (int k = 0; k < 8; ++k) {
            s1 += vv[k].x + vv[k].y + vv[k].z + vv[k].w;
            s2 += vv[k].x*vv[k].x + vv[k].y*vv[k].y + vv[k].z*vv[k].z + vv[k].w*vv[k].w;
        }
        s1 += __shfl_xor(s1, 1); s2 += __shfl_xor(s2, 1);
        s1 += __shfl_xor(s1, 2); s2 += __shfl_xor(s2, 2);
        const float mu = s1 * (1.0f/128.0f);
        const float rs = rsqrtf(s2 * (1.0f/128.0f) - mu*mu + LN_EPS);
        unsigned char* row = xnb[st & 1] + r_a*256;
        #pragma unroll
        for (int m = 0; m < 4; ++m) {
            const f32x4 a = vv[2*m], b = vv[2*m+1];
            union { short8 s8; uint32_t u[4]; } sv;
            sv.u[0] = cvt_pk_bf16((a.x - mu)*rs, (a.y - mu)*rs);
            sv.u[1] = cvt_pk_bf16((a.z - mu)*rs, (a.w - mu)*rs);
            sv.u[2] = cvt_pk_bf16((b.x - mu)*rs, (b.y - mu)*rs);
            sv.u[3] = cvt_pk_bf16((b.z - mu)*rs, (b.w - mu)*rs);
            *(short8*)(row + (((q_a*4 + m) ^ rx) << 4)) = sv.s8;
        }
    };

    // GEMM + activation chunk st: xnb[st&1] -> cvb[st&1]
    auto phaseG = [&](int st) {
        const int bx = st & 1;
        #pragma unroll
        for (int mt = 0; mt < 2; ++mt) {
            const unsigned char* rowp = xnb[bx] + (mt*16 + l15)*256;
            short8 af[4];
            #pragma unroll
            for (int kt = 0; kt < 4; ++kt) {
                const int c = (kt << 2) | lhi;
                af[kt] = *(const short8*)(rowp + ((c ^ (l15 & 7)) << 4));
            }
            f32x4 ag = (f32x4)(0.f), ah = (f32x4)(0.f);
            #pragma unroll
            for (int kt = 0; kt < 4; ++kt) {
                ag = __builtin_amdgcn_mfma_f32_16x16x32_bf16(af[kt], wfr[0][kt], ag, 0, 0, 0);
                ah = __builtin_amdgcn_mfma_f32_16x16x32_bf16(af[kt], wfr[1][kt], ah, 0, 0, 0);
            }
            const int d = gw*16 + l15;                       // 0..127
            #pragma unroll
            for (int j = 0; j < 4; ++j) {
                const int ls = mt*16 + lhi*4 + j;
                const float g  = ag[j] + bs2[0];
                const float hh = ah[j] + bs2[1];
                const float c  = 1.0f / (1.0f + __expf(g));
                const float ga = (hh >= 0.0f) ? (hh + 0.5f)
                                              : (1.0f / (1.0f + __expf(-hh)));
                cvb[bx][ls][d] = make_float2(c, (1.0f - c) * ga);
            }
        }
    };

    // scan chunk st (w0-1): cvb[st&1] -> out
    auto phaseC = [&](int st) {
        const int bc = st & 1;
        float* op = out + base_bt + (size_t)st * CH * rowstride + tid;
        #pragma unroll 8
        for (int ls = 0; ls < CH; ++ls) {
            const float2 cv = cvb[bc][ls][tid];
            h = fmaf(cv.x, h, cv.y);
            op[(size_t)ls * rowstride] = h;
        }
    };

    // ---- prologue: stage x(0), x(1) (w2-3; 16 loads in flight per wave) ----
    if (w == 2 || w == 3) { stageX(0); stageX(1); }

    // ---- pipeline: NCH+2 stages, one barrier each ----
    for (int st = 0; st <= NCH + 1; ++st) {
        if (w >= 4) {
            if (st >= 1 && st <= NCH) phaseG(st - 1);
        } else if (w >= 2) {
            if (st < NCH) {
                // x(st) landed; x(st+1)'s 8 loads stay in flight
                if (st + 1 < NCH) asm volatile("s_waitcnt vmcnt(8)" ::: "memory");
                else              asm volatile("s_waitcnt vmcnt(0)" ::: "memory");
                phaseLN(st);
                if (st + 2 < NCH) stageX(st + 2);
            }
        } else {
            if (st >= 2) phaseC(st - 2);
        }
        BAR();
    }
    if (tid < 128) nexth[(size_t)blockIdx.x * 128 + tid] = h;
}

extern "C" void kernel_launch(void* const* d_in, const int* in_sizes, int n_in,
                              void* d_out, int out_size, void* d_ws, size_t ws_size,
                              hipStream_t stream) {
    const float* x     = (const float*)d_in[0];
    const float* prevh = (const float*)d_in[1];
    const float* gamma = (const float*)d_in[2];
    const float* beta  = (const float*)d_in[3];
    const float* W     = (const float*)d_in[4];
    const float* bias  = (const float*)d_in[5];

    float* out   = (float*)d_out;
    float* nexth = out + (size_t)BB*SS*TT*DD;              // 16777216

    unsigned short* wf  = (unsigned short*)d_ws;           // 64 KB fragments
    float*          bpf = (float*)((char*)d_ws + 65536);   // 1 KB folded bias

    k0_pack<<<129, 256, 0, stream>>>(W, gamma, beta, bias, wf, bpf);
    fused_mingru<<<BB*TT, 768, 0, stream>>>(x, prevh, wf, bpf, out, nexth);
}

// Round 10
// 42.910 us; speedup vs baseline: 3.1041x; 1.1090x over previous
//
#include <hip/hip_runtime.h>
#include <hip/hip_bf16.h>
#include <stdint.h>

// Problem constants
#define BB 16
#define SS 512
#define TT 16
#define DD 128
#define CH 64                 // s-rows per stage
#define NCH (SS/CH)           // 8
#define LN_EPS 1e-5f

typedef __attribute__((ext_vector_type(8))) short short8;
typedef __attribute__((ext_vector_type(4))) float f32x4;

// HW packed f32->bf16 (RNE): dst.lo = src0, dst.hi = src1
static __device__ __forceinline__ uint32_t cvt_pk_bf16(float lo, float hi) {
    uint32_t r;
    asm("v_cvt_pk_bf16_f32 %0, %1, %2" : "=v"(r) : "v"(lo), "v"(hi));
    return r;
}

// LDS-ordering barrier: does NOT drain vmcnt (register x-prefetch and
// fire-and-forget out-stores stay in flight across it).
#define BAR() do {                                            \
    asm volatile("s_waitcnt lgkmcnt(0)" ::: "memory");        \
    __builtin_amdgcn_s_barrier();                             \
    asm volatile("" ::: "memory");                            \
} while (0)

// -----------------------------------------------------------------------------
// Single fused kernel. One block per (b,t) chain, 512 threads = 8 waves
// (2/SIMD). All waves homogeneous; ONE barrier per stage.
//
// Wave w owns output columns [w*16, w*16+16) (gate n-tile w, hidden n-tile 8+w).
// Per stage (64 rows):
//   phaseG(st): 4 m-tiles: ds_read A-frags -> 8 MFMA -> activation (c,v in regs)
//               -> IN-REGISTER scan via transform composition:
//               lane-local 4-row prefix, Hillis-Steele over lhi groups
//               (__shfl_up 16/32), broadcast of the m-tile composite, out stores.
//               Chunk carry = one register hM per lane (replicated over lhi).
//   phaseLN(st+1): 8 threads/row LayerNorm from register-prefetched x,
//               bf16 via cvt_pk, swizzled LDS write.
//   issuePx(st+2): register prefetch of next-next x chunk (16 VGPR).
// W fragments + folded bias are built in the prologue from W/gamma/beta/bias
// (no pre-pack kernel, no workspace).
// -----------------------------------------------------------------------------
__global__ __launch_bounds__(512, 2) void fused_mingru(
    const float* __restrict__ x, const float* __restrict__ prevh,
    const float* __restrict__ gamma, const float* __restrict__ beta,
    const float* __restrict__ W, const float* __restrict__ bias,
    float* __restrict__ out, float* __restrict__ nexth)
{
    __shared__ __align__(16) unsigned char xnb[2][CH*256];  // 2 x 16 KB bf16 xn

    const int tid  = threadIdx.x;
    const int w    = tid >> 6;           // 0..7
    const int lane = tid & 63;
    const int l15  = lane & 15;
    const int lhi  = lane >> 4;

    const int bt = blockIdx.x;
    const size_t rowstride = (size_t)TT * DD;               // 2048
    const size_t base_bt   = ((size_t)(bt >> 4) * SS * TT + (bt & 15)) * DD;

    // ---- LN lane assignment: 8 threads per row ----
    const int r_ln  = tid >> 3;          // row 0..63 within chunk
    const int c8    = tid & 7;           // 16-float slot within the row
    const int rx_ln = r_ln & 7;
    const float* xp0 = x + base_bt + (size_t)r_ln * rowstride + c8*16;

    // ---- register prefetch of x chunk (16 VGPR) ----
    f32x4 px0, px1, px2, px3;
    auto issuePx = [&](int st) {
        const float* xp = xp0 + (size_t)st * CH * rowstride;
        px0 = *(const f32x4*)(xp + 0);
        px1 = *(const f32x4*)(xp + 4);
        px2 = *(const f32x4*)(xp + 8);
        px3 = *(const f32x4*)(xp + 12);
    };
    issuePx(0);   // latency hidden under the W-fragment build below

    // ---- build W fragments + folded bias in-kernel ----
    // wfr[ni][kt] elem e <-> k = kt*32 + lhi*8 + e, col = (ni?128:0)+w*16+l15
    // bs2[ni] = bias[col] + sum_k beta[k]*W[k][col]   (cross-lhi shuffle reduce)
    short8 wfr[2][4];
    float  bs2[2];
    #pragma unroll
    for (int ni = 0; ni < 2; ++ni) {
        const int col = (ni ? 128 : 0) + w*16 + l15;
        float acc = 0.0f;
        #pragma unroll
        for (int kt = 0; kt < 4; ++kt) {
            union { short8 s8; uint32_t u[4]; } fr;
            #pragma unroll
            for (int p = 0; p < 4; ++p) {
                const int k0 = kt*32 + lhi*8 + 2*p;
                const float w0 = W[(size_t)k0*256 + col];
                const float w1 = W[(size_t)(k0+1)*256 + col];
                acc = fmaf(beta[k0],   w0, acc);
                acc = fmaf(beta[k0+1], w1, acc);
                fr.u[p] = cvt_pk_bf16(gamma[k0]*w0, gamma[k0+1]*w1);
            }
            wfr[ni][kt] = fr.s8;
        }
        acc += __shfl_xor(acc, 16);
        acc += __shfl_xor(acc, 32);      // sum over all 4 lhi groups (128 k)
        bs2[ni] = bias[col] + acc;
    }

    // running h for this wave's 16 columns (replicated across lhi groups)
    float hM = prevh[(size_t)bt*128 + w*16 + l15];

    // ---- LN: consume px regs -> xnb[st&1] (swizzled bf16) ----
    auto phaseLN = [&](int st) {
        float s1 = px0.x+px0.y+px0.z+px0.w + px1.x+px1.y+px1.z+px1.w
                 + px2.x+px2.y+px2.z+px2.w + px3.x+px3.y+px3.z+px3.w;
        float s2 = px0.x*px0.x+px0.y*px0.y+px0.z*px0.z+px0.w*px0.w
                 + px1.x*px1.x+px1.y*px1.y+px1.z*px1.z+px1.w*px1.w
                 + px2.x*px2.x+px2.y*px2.y+px2.z*px2.z+px2.w*px2.w
                 + px3.x*px3.x+px3.y*px3.y+px3.z*px3.z+px3.w*px3.w;
        s1 += __shfl_xor(s1, 1); s2 += __shfl_xor(s2, 1);
        s1 += __shfl_xor(s1, 2); s2 += __shfl_xor(s2, 2);
        s1 += __shfl_xor(s1, 4); s2 += __shfl_xor(s2, 4);
        const float mu = s1 * (1.0f/128.0f);
        const float rs = rsqrtf(s2 * (1.0f/128.0f) - mu*mu + LN_EPS);
        unsigned char* row = xnb[st & 1] + r_ln*256;
        union { short8 s8; uint32_t u[4]; } a, b2;
        a.u[0]  = cvt_pk_bf16((px0.x-mu)*rs, (px0.y-mu)*rs);
        a.u[1]  = cvt_pk_bf16((px0.z-mu)*rs, (px0.w-mu)*rs);
        a.u[2]  = cvt_pk_bf16((px1.x-mu)*rs, (px1.y-mu)*rs);
        a.u[3]  = cvt_pk_bf16((px1.z-mu)*rs, (px1.w-mu)*rs);
        b2.u[0] = cvt_pk_bf16((px2.x-mu)*rs, (px2.y-mu)*rs);
        b2.u[1] = cvt_pk_bf16((px2.z-mu)*rs, (px2.w-mu)*rs);
        b2.u[2] = cvt_pk_bf16((px3.x-mu)*rs, (px3.y-mu)*rs);
        b2.u[3] = cvt_pk_bf16((px3.z-mu)*rs, (px3.w-mu)*rs);
        *(short8*)(row + (((2*c8)     ^ rx_ln) << 4)) = a.s8;
        *(short8*)(row + (((2*c8 + 1) ^ rx_ln) << 4)) = b2.s8;
    };

    // ---- GEMM + activation + in-register scan + out stores ----
    auto phaseG = [&](int st) {
        const unsigned char* xb = xnb[st & 1];
        #pragma unroll
        for (int mt = 0; mt < 4; ++mt) {
            const unsigned char* rowp = xb + (mt*16 + l15)*256;
            short8 af[4];
            #pragma unroll
            for (int kt = 0; kt < 4; ++kt) {
                const int c = (kt << 2) | lhi;
                af[kt] = *(const short8*)(rowp + ((c ^ (l15 & 7)) << 4));
            }
            f32x4 ag = (f32x4)(0.f), ah = (f32x4)(0.f);
            #pragma unroll
            for (int kt = 0; kt < 4; ++kt) {
                ag = __builtin_amdgcn_mfma_f32_16x16x32_bf16(af[kt], wfr[0][kt], ag, 0, 0, 0);
                ah = __builtin_amdgcn_mfma_f32_16x16x32_bf16(af[kt], wfr[1][kt], ah, 0, 0, 0);
            }
            // activation -> (c,v); lane-local inclusive prefixes over its 4 rows
            float Lc[4], Lv[4];
            #pragma unroll
            for (int j = 0; j < 4; ++j) {
                const float g  = ag[j] + bs2[0];
                const float hh = ah[j] + bs2[1];
                const float cc = 1.0f / (1.0f + __expf(g));
                const float ga = (hh >= 0.0f) ? (hh + 0.5f)
                                              : (1.0f / (1.0f + __expf(-hh)));
                const float vv = (1.0f - cc) * ga;
                if (j == 0) { Lc[0] = cc; Lv[0] = vv; }
                else        { Lc[j] = cc * Lc[j-1]; Lv[j] = fmaf(cc, Lv[j-1], vv); }
            }
            // Hillis-Steele inclusive scan of 4-row transforms over lhi groups
            // compose(prev,cur): (Ccur*Cprev, Ccur*Vprev + Vcur)
            float Ic = Lc[3], Iv = Lv[3];
            float pc = __shfl_up(Ic, 16), pv = __shfl_up(Iv, 16);
            if (lhi >= 1) { Iv = fmaf(Ic, pv, Iv); Ic *= pc; }
            pc = __shfl_up(Ic, 32); pv = __shfl_up(Iv, 32);
            if (lhi >= 2) { Iv = fmaf(Ic, pv, Iv); Ic *= pc; }
            // exclusive prefix for this group; full m-tile composite from lhi=3
            float Ec = __shfl_up(Ic, 16), Ev = __shfl_up(Iv, 16);
            if (lhi == 0) { Ec = 1.0f; Ev = 0.0f; }
            const float Mc = __shfl(Ic, 48 + l15);
            const float Mv = __shfl(Iv, 48 + l15);
            // h before this lane's first row; outputs; advance chunk carry
            const float hE = fmaf(Ec, hM, Ev);
            float* op = out + base_bt
                      + (size_t)(st*CH + mt*16 + lhi*4) * rowstride + w*16 + l15;
            #pragma unroll
            for (int j = 0; j < 4; ++j)
                op[(size_t)j * rowstride] = fmaf(Lc[j], hE, Lv[j]);
            hM = fmaf(Mc, hM, Mv);
        }
    };

    // ---- prologue: LN(0) (waits px0), prefetch x(1) ----
    phaseLN(0);
    issuePx(1);
    BAR();

    // ---- main: one barrier per stage ----
    for (int st = 0; st < NCH; ++st) {
        phaseG(st);
        if (st + 1 < NCH) {
            phaseLN(st + 1);                 // consumes px(st+1)
            if (st + 2 < NCH) issuePx(st + 2);
        }
        BAR();
    }

    if (lane < 16)
        nexth[(size_t)bt*128 + w*16 + lane] = hM;
}

extern "C" void kernel_launch(void* const* d_in, const int* in_sizes, int n_in,
                              void* d_out, int out_size, void* d_ws, size_t ws_size,
                              hipStream_t stream) {
    const float* x     = (const float*)d_in[0];
    const float* prevh = (const float*)d_in[1];
    const float* gamma = (const float*)d_in[2];
    const float* beta  = (const float*)d_in[3];
    const float* W     = (const float*)d_in[4];
    const float* bias  = (const float*)d_in[5];

    float* out   = (float*)d_out;
    float* nexth = out + (size_t)BB*SS*TT*DD;              // 16777216

    fused_mingru<<<BB*TT, 512, 0, stream>>>(x, prevh, gamma, beta, W, bias,
                                            out, nexth);
}

// Round 12
// 41.925 us; speedup vs baseline: 3.1770x; 1.0235x over previous
//
#include <hip/hip_runtime.h>
#include <hip/hip_bf16.h>
#include <stdint.h>

// Problem constants
#define BB 16
#define SS 512
#define TT 16
#define DD 128
#define CH 64                 // s-rows per stage
#define NCH (SS/CH)           // 8
#define LN_EPS 1e-5f

typedef __attribute__((ext_vector_type(8))) short short8;
typedef __attribute__((ext_vector_type(4))) float f32x4;

// HW packed f32->bf16 (RNE): dst.lo = src0, dst.hi = src1
static __device__ __forceinline__ uint32_t cvt_pk_bf16(float lo, float hi) {
    uint32_t r;
    asm("v_cvt_pk_bf16_f32 %0, %1, %2" : "=v"(r) : "v"(lo), "v"(hi));
    return r;
}

// LDS-ordering barrier: does NOT drain vmcnt.
#define BAR() do {                                            \
    asm volatile("s_waitcnt lgkmcnt(0)" ::: "memory");        \
    __builtin_amdgcn_s_barrier();                             \
    asm volatile("" ::: "memory");                            \
} while (0)

// -----------------------------------------------------------------------------
// Single fused kernel. One block per (b,t) chain, 512 threads = 8 waves.
// Wave w owns output cols [w*16, w*16+16). One barrier per 64-row stage.
//
// ROW PERMUTATION: LN writes s-row s to A-slot (mt*16 + lhi*4 + j) where
// s = lhi*16 + mt*4 + j. Hence MFMA C-reg (mt, lhi, j) holds s = lhi*16+mt*4+j,
// i.e. each lane owns 16 CONSECUTIVE s-rows. The stage scan is then:
//   - 4 independent m-tile MFMA+activation passes (c,v -> 32 regs, no serial dep)
//   - one lane-local 16-step prefix compose (pure VALU)
//   - one cross-lhi Hillis-Steele (2 shuffle rounds) + exclusive + broadcast
//   - 16 out stores; hM advances once per stage.
// -----------------------------------------------------------------------------
__global__ __launch_bounds__(512, 2) void fused_mingru(
    const float* __restrict__ x, const float* __restrict__ prevh,
    const float* __restrict__ gamma, const float* __restrict__ beta,
    const float* __restrict__ W, const float* __restrict__ bias,
    float* __restrict__ out, float* __restrict__ nexth)
{
    __shared__ __align__(16) unsigned char xnb[2][CH*256];  // 2 x 16 KB bf16 xn

    const int tid  = threadIdx.x;
    const int w    = tid >> 6;           // 0..7
    const int lane = tid & 63;
    const int l15  = lane & 15;
    const int lhi  = lane >> 4;

    const int bt = blockIdx.x;
    const size_t rowstride = (size_t)TT * DD;               // 2048
    const size_t base_bt   = ((size_t)(bt >> 4) * SS * TT + (bt & 15)) * DD;

    // ---- LN lane assignment: 8 threads per row ----
    const int r_ln = tid >> 3;           // s-row 0..63 within chunk
    const int c8   = tid & 7;            // 16-float slot within the row
    // permuted A-slot for this s-row
    const int slot_p = ((r_ln >> 2) & 3)*16 + (r_ln >> 4)*4 + (r_ln & 3);
    const int keyx   = slot_p & 7;
    const float* xp0 = x + base_bt + (size_t)r_ln * rowstride + c8*16;

    // ---- register prefetch of x chunk (16 VGPR) ----
    f32x4 px0, px1, px2, px3;
    auto issuePx = [&](int st) {
        const float* xp = xp0 + (size_t)st * CH * rowstride;
        px0 = *(const f32x4*)(xp + 0);
        px1 = *(const f32x4*)(xp + 4);
        px2 = *(const f32x4*)(xp + 8);
        px3 = *(const f32x4*)(xp + 12);
    };
    issuePx(0);   // latency hidden under the W-fragment build

    // ---- build W fragments + folded bias in-kernel ----
    short8 wfr[2][4];
    float  bs2[2];
    #pragma unroll
    for (int ni = 0; ni < 2; ++ni) {
        const int col = (ni ? 128 : 0) + w*16 + l15;
        float acc = 0.0f;
        #pragma unroll
        for (int kt = 0; kt < 4; ++kt) {
            union { short8 s8; uint32_t u[4]; } fr;
            #pragma unroll
            for (int p = 0; p < 4; ++p) {
                const int k0 = kt*32 + lhi*8 + 2*p;
                const float w0 = W[(size_t)k0*256 + col];
                const float w1 = W[(size_t)(k0+1)*256 + col];
                acc = fmaf(beta[k0],   w0, acc);
                acc = fmaf(beta[k0+1], w1, acc);
                fr.u[p] = cvt_pk_bf16(gamma[k0]*w0, gamma[k0+1]*w1);
            }
            wfr[ni][kt] = fr.s8;
        }
        acc += __shfl_xor(acc, 16);
        acc += __shfl_xor(acc, 32);
        bs2[ni] = bias[col] + acc;
    }

    // running h for this wave's 16 columns (replicated across lhi groups)
    float hM = prevh[(size_t)bt*128 + w*16 + l15];

    // ---- LN: consume px regs -> xnb[st&1] at permuted slot (swizzled) ----
    auto phaseLN = [&](int st) {
        float s1 = px0.x+px0.y+px0.z+px0.w + px1.x+px1.y+px1.z+px1.w
                 + px2.x+px2.y+px2.z+px2.w + px3.x+px3.y+px3.z+px3.w;
        float s2 = px0.x*px0.x+px0.y*px0.y+px0.z*px0.z+px0.w*px0.w
                 + px1.x*px1.x+px1.y*px1.y+px1.z*px1.z+px1.w*px1.w
                 + px2.x*px2.x+px2.y*px2.y+px2.z*px2.z+px2.w*px2.w
                 + px3.x*px3.x+px3.y*px3.y+px3.z*px3.z+px3.w*px3.w;
        s1 += __shfl_xor(s1, 1); s2 += __shfl_xor(s2, 1);
        s1 += __shfl_xor(s1, 2); s2 += __shfl_xor(s2, 2);
        s1 += __shfl_xor(s1, 4); s2 += __shfl_xor(s2, 4);
        const float mu = s1 * (1.0f/128.0f);
        const float rs = rsqrtf(s2 * (1.0f/128.0f) - mu*mu + LN_EPS);
        unsigned char* row = xnb[st & 1] + slot_p*256;
        union { short8 s8; uint32_t u[4]; } a, b2;
        a.u[0]  = cvt_pk_bf16((px0.x-mu)*rs, (px0.y-mu)*rs);
        a.u[1]  = cvt_pk_bf16((px0.z-mu)*rs, (px0.w-mu)*rs);
        a.u[2]  = cvt_pk_bf16((px1.x-mu)*rs, (px1.y-mu)*rs);
        a.u[3]  = cvt_pk_bf16((px1.z-mu)*rs, (px1.w-mu)*rs);
        b2.u[0] = cvt_pk_bf16((px2.x-mu)*rs, (px2.y-mu)*rs);
        b2.u[1] = cvt_pk_bf16((px2.z-mu)*rs, (px2.w-mu)*rs);
        b2.u[2] = cvt_pk_bf16((px3.x-mu)*rs, (px3.y-mu)*rs);
        b2.u[3] = cvt_pk_bf16((px3.z-mu)*rs, (px3.w-mu)*rs);
        *(short8*)(row + (((2*c8)     ^ keyx) << 4)) = a.s8;
        *(short8*)(row + (((2*c8 + 1) ^ keyx) << 4)) = b2.s8;
    };

    // ---- GEMM + activation + stage-wide in-register scan + out stores ----
    auto phaseG = [&](int st) {
        const unsigned char* xb = xnb[st & 1];
        float Cc[16], Cv[16];            // s = lhi*16 + idx, idx = mt*4 + j
        #pragma unroll
        for (int mt = 0; mt < 4; ++mt) {
            const unsigned char* rowp = xb + (mt*16 + l15)*256;
            short8 af[4];
            #pragma unroll
            for (int kt = 0; kt < 4; ++kt) {
                const int c = (kt << 2) | lhi;
                af[kt] = *(const short8*)(rowp + ((c ^ (l15 & 7)) << 4));
            }
            f32x4 ag = (f32x4)(0.f), ah = (f32x4)(0.f);
            #pragma unroll
            for (int kt = 0; kt < 4; ++kt) {
                ag = __builtin_amdgcn_mfma_f32_16x16x32_bf16(af[kt], wfr[0][kt], ag, 0, 0, 0);
                ah = __builtin_amdgcn_mfma_f32_16x16x32_bf16(af[kt], wfr[1][kt], ah, 0, 0, 0);
            }
            #pragma unroll
            for (int j = 0; j < 4; ++j) {
                const float g  = ag[j] + bs2[0];
                const float hh = ah[j] + bs2[1];
                const float cc = 1.0f / (1.0f + __expf(g));
                const float ga = (hh >= 0.0f) ? (hh + 0.5f)
                                              : (1.0f / (1.0f + __expf(-hh)));
                Cc[mt*4 + j] = cc;
                Cv[mt*4 + j] = (1.0f - cc) * ga;
            }
        }
        // lane-local inclusive prefix over 16 consecutive s-rows
        #pragma unroll
        for (int i = 1; i < 16; ++i) {
            Cv[i] = fmaf(Cc[i], Cv[i-1], Cv[i]);
            Cc[i] = Cc[i] * Cc[i-1];
        }
        // cross-lhi Hillis-Steele on 16-row composites
        float Ic = Cc[15], Iv = Cv[15];
        float pc = __shfl_up(Ic, 16), pv = __shfl_up(Iv, 16);
        if (lhi >= 1) { Iv = fmaf(Ic, pv, Iv); Ic *= pc; }
        pc = __shfl_up(Ic, 32); pv = __shfl_up(Iv, 32);
        if (lhi >= 2) { Iv = fmaf(Ic, pv, Iv); Ic *= pc; }
        // exclusive prefix for this lhi group; stage composite from lhi=3
        float Ec = __shfl_up(Ic, 16), Ev = __shfl_up(Iv, 16);
        if (lhi == 0) { Ec = 1.0f; Ev = 0.0f; }
        const float Mc = __shfl(Ic, 48 + l15);
        const float Mv = __shfl(Iv, 48 + l15);
        const float hE = fmaf(Ec, hM, Ev);   // h before row lhi*16
        float* op = out + base_bt + (size_t)(st*CH + lhi*16) * rowstride + w*16 + l15;
        #pragma unroll
        for (int i = 0; i < 16; ++i)
            op[(size_t)i * rowstride] = fmaf(Cc[i], hE, Cv[i]);
        hM = fmaf(Mc, hM, Mv);
    };

    // ---- prologue: LN(0) (waits px0), prefetch x(1) ----
    phaseLN(0);
    issuePx(1);
    BAR();

    // ---- main: one barrier per stage ----
    for (int st = 0; st < NCH; ++st) {
        phaseG(st);
        if (st + 1 < NCH) {
            phaseLN(st + 1);                 // consumes px(st+1)
            if (st + 2 < NCH) issuePx(st + 2);
        }
        BAR();
    }

    if (lane < 16)
        nexth[(size_t)bt*128 + w*16 + lane] = hM;
}

extern "C" void kernel_launch(void* const* d_in, const int* in_sizes, int n_in,
                              void* d_out, int out_size, void* d_ws, size_t ws_size,
                              hipStream_t stream) {
    const float* x     = (const float*)d_in[0];
    const float* prevh = (const float*)d_in[1];
    const float* gamma = (const float*)d_in[2];
    const float* beta  = (const float*)d_in[3];
    const float* W     = (const float*)d_in[4];
    const float* bias  = (const float*)d_in[5];

    float* out   = (float*)d_out;
    float* nexth = out + (size_t)BB*SS*TT*DD;              // 16777216

    fused_mingru<<<BB*TT, 512, 0, stream>>>(x, prevh, gamma, beta, W, bias,
                                            out, nexth);
}